// Round 3
// baseline (12925.400 us; speedup 1.0000x reference)
//
#include <hip/hip_runtime.h>
#include <hip/hip_cooperative_groups.h>
#include <math.h>

namespace cg = cooperative_groups;

#define SLEN 64
#define BATCH 256
#define VIND 128
#define VOUTD 128
#define UDIM 1024
#define EDIM 512
#define TDEC 25
#define GXW 1536
#define U3 3072
#define NSEG 12

typedef __attribute__((ext_vector_type(8))) short short8;
typedef __attribute__((ext_vector_type(4))) float f32x4;

#define MFMA(acc, A, B) acc = __builtin_amdgcn_mfma_f32_16x16x32_bf16((A), (B), (acc), 0, 0, 0)

// libm sigmoid/tanh in the RECURRENT path (gates): fast variants drift over the
// 64-step encoder + 24-step decoder recurrence and flip greedy argmax (R1 fail).
__device__ __forceinline__ float sigm(float x) { return 1.f / (1.f + expf(-x)); }

// fast tanh for the attention SCORE path only (non-recurrent-critical)
__device__ __forceinline__ float tanhf_fast(float x) {
    float ax = fabsf(x);
    float e = __expf(-2.f * ax);
    float t = (1.f - e) / (1.f + e);
    return copysignf(t, x);
}

__device__ __forceinline__ short f2bf(float f) {
    unsigned u = __float_as_uint(f);
    u += 0x7FFF + ((u >> 16) & 1);
    return (short)(u >> 16);
}
__device__ __forceinline__ float bf2f(short h) {
    return __uint_as_float(((unsigned)(unsigned short)h) << 16);
}

// fragment-major packed layout for operand X[R][K]:
// chunk(r,k) holds X[r][k..k+8); lane = (r&15) + 16*((k>>3)&3)
__device__ __forceinline__ size_t pkChunk(int r, int k, int K) {
    return ((size_t)(r >> 4) * (K >> 5) + (k >> 5)) * 64 + ((r & 15) + 16 * ((k >> 3) & 3));
}

union S8 { short s[8]; short8 v; };

__device__ __forceinline__ void writeSplit8(short* Hi, short* Lo, size_t chunk,
                                            const float* vals) {
    S8 h, l;
#pragma unroll
    for (int j = 0; j < 8; j++) {
        short hb = f2bf(vals[j]);
        h.s[j] = hb;
        l.s[j] = f2bf(vals[j] - bf2f(hb));
    }
    ((short8*)Hi)[chunk] = h.v;
    ((short8*)Lo)[chunk] = l.v;
}

// ---------------------------------------------------------------------------
__global__ void init_kernel(float* __restrict__ h0, short* __restrict__ hpHi,
                            short* __restrict__ hpLo, float* __restrict__ out0,
                            int* __restrict__ idx,
                            const float* __restrict__ o2h_W,
                            const float* __restrict__ o2h_b,
                            float* __restrict__ o2hT) {
    int i = blockIdx.x * 256 + threadIdx.x;
    if (i < BATCH * UDIM) { h0[i] = 0.f; hpHi[i] = 0; hpLo[i] = 0; }
    if (i < BATCH * VOUTD) out0[i] = ((i & (VOUTD - 1)) == 0) ? 1.f : 0.f;
    if (i < BATCH) idx[i] = 0;
    if (i < VOUTD * EDIM) {
        // o2hT[v][e] = o2h_W[e][v] + o2h_b[e]  (bias folded, row-read at decode)
        int v = i >> 9, e = i & (EDIM - 1);
        o2hT[i] = o2h_W[(size_t)e * VOUTD + v] + o2h_b[e];
    }
}

// ---------------------------------------------------------------------------
// All weight/input packing in ONE kernel: segment table passed by value.
// ---------------------------------------------------------------------------
struct PackSeg {
    const float* sA; const float* sB;
    short* Hi; short* Lo;
    int KA, KB, offA, offB, chunkStart;
};
struct PackArgs { PackSeg s[NSEG]; };

__global__ void pack_all(PackArgs pa, int total) {
    int gid = blockIdx.x * 256 + threadIdx.x;
    if (gid >= total) return;
    int si = 0;
#pragma unroll
    for (int i = 1; i < NSEG; i++) si = (gid >= pa.s[i].chunkStart) ? i : si;
    PackSeg sg = pa.s[si];
    int local = gid - sg.chunkStart;
    int K = sg.KA + sg.KB;
    int cpr = K >> 3;
    int r = local / cpr, k0 = (local - r * cpr) * 8;
    const float* src = (k0 < sg.KA)
        ? sg.sA + (size_t)(sg.offA + r) * sg.KA + k0
        : sg.sB + (size_t)(sg.offB + r) * sg.KB + (k0 - sg.KA);
    float v[8];
#pragma unroll
    for (int j = 0; j < 8; j++) v[j] = src[j];
    writeSplit8(sg.Hi, sg.Lo, pkChunk(r, k0, K), v);
}

// ---------------------------------------------------------------------------
// Split-bf16 3-pass MFMA GEMM, BM=64 x BN=128 block (4 waves of 32x64).
// ---------------------------------------------------------------------------
__global__ __launch_bounds__(256) void gemm_w(
    const short8* __restrict__ Ahi, const short8* __restrict__ Alo,
    const short8* __restrict__ Whi, const short8* __restrict__ Wlo,
    const float* __restrict__ bias, float* __restrict__ C,
    int KT, int N) {
    int tid = threadIdx.x, lane = tid & 63, wave = tid >> 6;
    int m16 = blockIdx.x * 4 + (wave & 1) * 2;
    int nb = blockIdx.y * 8 + (wave >> 1) * 4;
    const short8* a0h = Ahi + (size_t)m16 * KT * 64 + lane;
    const short8* a1h = a0h + (size_t)KT * 64;
    const short8* a0l = Alo + (size_t)m16 * KT * 64 + lane;
    const short8* a1l = a0l + (size_t)KT * 64;
    const short8* w0h = Whi + (size_t)(nb + 0) * KT * 64 + lane;
    const short8* w1h = Whi + (size_t)(nb + 1) * KT * 64 + lane;
    const short8* w2h = Whi + (size_t)(nb + 2) * KT * 64 + lane;
    const short8* w3h = Whi + (size_t)(nb + 3) * KT * 64 + lane;
    const short8* w0l = Wlo + (size_t)(nb + 0) * KT * 64 + lane;
    const short8* w1l = Wlo + (size_t)(nb + 1) * KT * 64 + lane;
    const short8* w2l = Wlo + (size_t)(nb + 2) * KT * 64 + lane;
    const short8* w3l = Wlo + (size_t)(nb + 3) * KT * 64 + lane;
    f32x4 acc0[4] = {}, acc1[4] = {};

    for (int kt = 0; kt < KT; kt++) {
        size_t o = (size_t)kt * 64;
        short8 A0H = a0h[o], A1H = a1h[o], A0L = a0l[o], A1L = a1l[o];
        short8 WH0 = w0h[o], WL0 = w0l[o];
        MFMA(acc0[0], A0H, WH0); MFMA(acc1[0], A1H, WH0);
        MFMA(acc0[0], A0H, WL0); MFMA(acc1[0], A1H, WL0);
        MFMA(acc0[0], A0L, WH0); MFMA(acc1[0], A1L, WH0);
        short8 WH1 = w1h[o], WL1 = w1l[o];
        MFMA(acc0[1], A0H, WH1); MFMA(acc1[1], A1H, WH1);
        MFMA(acc0[1], A0H, WL1); MFMA(acc1[1], A1H, WL1);
        MFMA(acc0[1], A0L, WH1); MFMA(acc1[1], A1L, WH1);
        short8 WH2 = w2h[o], WL2 = w2l[o];
        MFMA(acc0[2], A0H, WH2); MFMA(acc1[2], A1H, WH2);
        MFMA(acc0[2], A0H, WL2); MFMA(acc1[2], A1H, WL2);
        MFMA(acc0[2], A0L, WH2); MFMA(acc1[2], A1L, WH2);
        short8 WH3 = w3h[o], WL3 = w3l[o];
        MFMA(acc0[3], A0H, WH3); MFMA(acc1[3], A1H, WH3);
        MFMA(acc0[3], A0H, WL3); MFMA(acc1[3], A1H, WL3);
        MFMA(acc0[3], A0L, WH3); MFMA(acc1[3], A1L, WH3);
    }
    int rsub = (lane >> 4) * 4, cn = lane & 15;
    int row0 = (m16 + 0) * 16 + rsub;
    int row1 = (m16 + 1) * 16 + rsub;
#pragma unroll
    for (int j = 0; j < 4; j++) {
        int col = (nb + j) * 16 + cn;
        float bb = bias ? bias[col] : 0.f;
#pragma unroll
        for (int r = 0; r < 4; r++) {
            C[(size_t)(row0 + r) * N + col] = acc0[j][r] + bb;
            C[(size_t)(row1 + r) * N + col] = acc1[j][r] + bb;
        }
    }
}

// ---------------------------------------------------------------------------
// BM=32 GEMM for the pre-loop tmp2. Grid (M/32, N/64).
// ---------------------------------------------------------------------------
__global__ __launch_bounds__(256) void gemm_bm32(
    const short8* __restrict__ Ahi, const short8* __restrict__ Alo,
    const short8* __restrict__ Whi, const short8* __restrict__ Wlo,
    const float* __restrict__ bias, float* __restrict__ C,
    int KT, int N) {
    int tid = threadIdx.x, lane = tid & 63, wave = tid >> 6;
    int m16 = blockIdx.x * 2 + (wave & 1);
    int n16 = blockIdx.y * 4 + (wave >> 1) * 2;
    const short8* ah = Ahi + (size_t)m16 * KT * 64 + lane;
    const short8* al = Alo + (size_t)m16 * KT * 64 + lane;
    const short8* w0h = Whi + (size_t)n16 * KT * 64 + lane;
    const short8* w1h = w0h + (size_t)KT * 64;
    const short8* w0l = Wlo + (size_t)n16 * KT * 64 + lane;
    const short8* w1l = w0l + (size_t)KT * 64;
    f32x4 a0 = {0,0,0,0}, a1 = {0,0,0,0};
    for (int kt = 0; kt < KT; kt++) {
        size_t o = (size_t)kt * 64;
        short8 AH = ah[o], AL = al[o];
        short8 W0H = w0h[o], W0L = w0l[o], W1H = w1h[o], W1L = w1l[o];
        MFMA(a0, AH, W0H); MFMA(a1, AH, W1H);
        MFMA(a0, AH, W0L); MFMA(a1, AH, W1L);
        MFMA(a0, AL, W0H); MFMA(a1, AL, W1H);
    }
    int rsub = (lane >> 4) * 4, cn = lane & 15;
    float b0 = bias ? bias[(n16 + 0) * 16 + cn] : 0.f;
    float b1 = bias ? bias[(n16 + 1) * 16 + cn] : 0.f;
#pragma unroll
    for (int r = 0; r < 4; r++) {
        int row = m16 * 16 + rsub + r;
        C[(size_t)row * N + (n16 + 0) * 16 + cn] = a0[r] + b0;
        C[(size_t)row * N + (n16 + 1) * 16 + cn] = a1[r] + b1;
    }
}

// ---------------------------------------------------------------------------
// Encoder GRU step: 6 waves (gate x K-half). Grid (64, 16) = 1024 blocks.
// ---------------------------------------------------------------------------
__global__ __launch_bounds__(384) void enc_gru3(
    const short8* __restrict__ hinH8, const short8* __restrict__ hinL8,
    const short8* __restrict__ WrH, const short8* __restrict__ WrL,
    const short8* __restrict__ WzH, const short8* __restrict__ WzL,
    const short8* __restrict__ WnH, const short8* __restrict__ WnL,
    const float* __restrict__ gi,
    const float* __restrict__ bih, const float* __restrict__ bhh,
    const float* __restrict__ hinF, float* __restrict__ houtF,
    short* __restrict__ hoH, short* __restrict__ hoL,
    short* __restrict__ eaHi, short* __restrict__ eaLo,
    const int* __restrict__ x_len, int t) {
    __shared__ float sC[6][16][16];
    __shared__ float sHo[16][16];
    __shared__ float sEo[16][16];
    int tid = threadIdx.x, lane = tid & 63, wave = tid >> 6;  // wave 0..5
    int g = blockIdx.x;
    int m16 = blockIdx.y;
    int gate = wave >> 1, half = wave & 1;
    const short8* ah = hinH8 + (size_t)m16 * 32 * 64 + (size_t)half * 16 * 64 + lane;
    const short8* al = hinL8 + (size_t)m16 * 32 * 64 + (size_t)half * 16 * 64 + lane;
    const short8* WH0 = (gate == 0) ? WrH : (gate == 1) ? WzH : WnH;
    const short8* WL0 = (gate == 0) ? WrL : (gate == 1) ? WzL : WnL;
    const short8* wh = WH0 + (size_t)g * 32 * 64 + (size_t)half * 16 * 64 + lane;
    const short8* wl = WL0 + (size_t)g * 32 * 64 + (size_t)half * 16 * 64 + lane;
    f32x4 acc = {0, 0, 0, 0};
    for (int kt = 0; kt < 16; kt++) {
        size_t o = (size_t)kt * 64;
        short8 AH = ah[o], AL = al[o];
        short8 WH = wh[o], WL = wl[o];
        MFMA(acc, AH, WH);
        MFMA(acc, AH, WL);
        MFMA(acc, AL, WH);
    }
    {
        int rsub = (lane >> 4) << 2, cn = lane & 15;
#pragma unroll
        for (int j = 0; j < 4; j++) sC[wave][rsub + j][cn] = acc[j];
    }
    __syncthreads();
    if (wave == 0) {
        int cu = g * 16 + (lane & 15);
        int rsub = (lane >> 4) << 2;
        float b_r = bih[cu] + bhh[cu];
        float b_z = bih[UDIM + cu] + bhh[UDIM + cu];
        float b_nh = bhh[2 * UDIM + cu];
        float b_ni = bih[2 * UDIM + cu];
        int growLocal = (t & 7) * 256;
#pragma unroll
        for (int j = 0; j < 4; j++) {
            int rr = rsub + j, cc = lane & 15;
            int b = m16 * 16 + rr;
            const float* gr = gi + (size_t)(growLocal + b) * U3;
            float rg = sigm(sC[0][rr][cc] + sC[1][rr][cc] + gr[cu] + b_r);
            float zg = sigm(sC[2][rr][cc] + sC[3][rr][cc] + gr[UDIM + cu] + b_z);
            float nn = tanhf(gr[2 * UDIM + cu] + b_ni +
                             rg * (sC[4][rr][cc] + sC[5][rr][cc] + b_nh));
            float hp = hinF[(size_t)b * UDIM + cu];
            float hv = (1.f - zg) * nn + zg * hp;
            bool msk = t < x_len[b];
            float ho = msk ? hv : hp;
            houtF[(size_t)b * UDIM + cu] = ho;
            sHo[rr][cc] = ho;
            sEo[rr][cc] = msk ? hv : 0.f;
        }
    }
    __syncthreads();
    if (wave == 1 && lane < 32) {
        int rr = lane >> 1, oct = lane & 1;
        int brow = m16 * 16 + rr;
        int u0 = g * 16 + oct * 8;
        float v[8];
#pragma unroll
        for (int j = 0; j < 8; j++) v[j] = sHo[rr][oct * 8 + j];
        writeSplit8(hoH, hoL, pkChunk(brow, u0, UDIM), v);
#pragma unroll
        for (int j = 0; j < 8; j++) v[j] = sEo[rr][oct * 8 + j];
        writeSplit8(eaHi, eaLo, pkChunk(brow * SLEN + t, u0, UDIM), v);
    }
}

// ---------------------------------------------------------------------------
// Persistent cooperative decoder: all 24 steps x {attn, gru, fc/W2} in ONE
// launch. Grid 256 blocks x 1024 threads = exactly 1 block/CU (co-resident);
// cg grid.sync() between phases replaces 72 kernel launches.
// Math is phase-for-phase identical to the R2 kernels (libm in recurrence).
// ---------------------------------------------------------------------------
struct DecArgs {
    const float* encProj;
    const short* eaHi; const short* eaLo;
    float* tmp2;
    const float* V_W; const float* V_b;
    const float* o2hT;
    int* idx;
    short* gxHi; short* gxLo;
    const short8 *dWrH, *dWrL, *dWzH, *dWzL, *dWnhH, *dWnhL, *dWniH, *dWniL;
    const float *bih, *bhh;
    float *hAF, *hBF;
    short *hAH, *hAL, *hBH, *hBL;
    const short8 *fcH, *fcL; const float* fc_b;
    const short8 *w2H, *w2L; const float* W2_b;
    float* out;
};

__global__ __launch_bounds__(1024, 4) void dec_persist(DecArgs A) {
    cg::grid_group grid = cg::this_grid();
    __shared__ union SMem {
        struct { float t2[UDIM]; float v[UDIM]; float attn[SLEN]; float part[7][128][9]; } a;
        struct { float sC[4][4][16][16]; float sHo[4][16][16]; } g;
        struct { float sP[16][129]; } f;
    } sm;
    const int bid = blockIdx.x, tid = threadIdx.x, lane = tid & 63, w = tid >> 6;
    const int gq = bid & 63, mq = bid >> 6;

    for (int st = 0; st < TDEC - 1; st++) {
        const float* hinF; float* houtF;
        const short *hiH, *hiL; short *hoH, *hoL;
        if (st & 1) { hinF = A.hBF; houtF = A.hAF; hiH = A.hBH; hiL = A.hBL; hoH = A.hAH; hoL = A.hAL; }
        else        { hinF = A.hAF; houtF = A.hBF; hiH = A.hAH; hiL = A.hAL; hoH = A.hBH; hoL = A.hBL; }

        // ============ Phase A: attention + ctx + emb -> gx (block = batch) ====
        {
            const int b = bid;
            for (int u = tid; u < UDIM; u += 1024) {
                sm.a.t2[u] = A.tmp2[(size_t)b * UDIM + u];
                sm.a.v[u] = A.V_W[u];
            }
            __syncthreads();
            for (int s = w; s < SLEN; s += 16) {
                const float4* ep4 = (const float4*)(A.encProj + ((size_t)b * SLEN + s) * UDIM);
                float p = 0.f;
                for (int u4 = lane; u4 < UDIM / 4; u4 += 64) {
                    float4 e = ep4[u4];
                    int u = 4 * u4;
                    p += tanhf_fast(e.x + sm.a.t2[u]) * sm.a.v[u] +
                         tanhf_fast(e.y + sm.a.t2[u + 1]) * sm.a.v[u + 1] +
                         tanhf_fast(e.z + sm.a.t2[u + 2]) * sm.a.v[u + 2] +
                         tanhf_fast(e.w + sm.a.t2[u + 3]) * sm.a.v[u + 3];
                }
#pragma unroll
                for (int off = 32; off > 0; off >>= 1) p += __shfl_xor(p, off);
                if (lane == 0) sm.a.attn[s] = p + A.V_b[0];
            }
            __syncthreads();
            if (tid < 64) {
                float v = sm.a.attn[tid];
                float mx = v;
#pragma unroll
                for (int off = 32; off > 0; off >>= 1) mx = fmaxf(mx, __shfl_xor(mx, off));
                float e = expf(v - mx);
                float sum = e;
#pragma unroll
                for (int off = 32; off > 0; off >>= 1) sum += __shfl_xor(sum, off);
                sm.a.attn[tid] = e / sum;
            }
            __syncthreads();
            {
                int grp = tid >> 7, tu = tid & 127;  // 8 s-groups x 128 u-threads
                int u0 = tu * 8;
                float a[8] = {0, 0, 0, 0, 0, 0, 0, 0};
                const short8* hi8 = (const short8*)A.eaHi;
                const short8* lo8 = (const short8*)A.eaLo;
                int lanePart = 16 * ((u0 >> 3) & 3);
                int colPart = u0 >> 5;
                for (int s = grp * 8; s < grp * 8 + 8; s++) {
                    int r = b * SLEN + s;
                    size_t ch = ((size_t)(r >> 4) * (UDIM >> 5) + colPart) * 64 + (r & 15) + lanePart;
                    S8 h, l;
                    h.v = hi8[ch];
                    l.v = lo8[ch];
                    float wt = sm.a.attn[s];
#pragma unroll
                    for (int j = 0; j < 8; j++) a[j] += wt * (bf2f(h.s[j]) + bf2f(l.s[j]));
                }
                if (grp) {
#pragma unroll
                    for (int j = 0; j < 8; j++) sm.a.part[grp - 1][tu][j] = a[j];
                }
                __syncthreads();
                if (tid < 128) {
#pragma unroll
                    for (int gg = 0; gg < 7; gg++)
#pragma unroll
                        for (int j = 0; j < 8; j++) a[j] += sm.a.part[gg][tu][j];
                    writeSplit8(A.gxHi, A.gxLo, pkChunk(b, u0, GXW), a);
                } else if (tid < 192) {
                    int e0 = (tid - 128) * 8;
                    int ib = A.idx[b];
                    const float* row = A.o2hT + (size_t)ib * EDIM + e0;
                    float v[8];
#pragma unroll
                    for (int j = 0; j < 8; j++) v[j] = row[j];
                    writeSplit8(A.gxHi, A.gxLo, pkChunk(b, UDIM + e0, GXW), v);
                }
            }
        }
        __threadfence();
        grid.sync();

        // ============ Phase G: decoder GRU (block = (gq, 4 batch-tiles)) ======
        {
            if (w < 12) {
                const int gate = w >> 2, mloc = w & 3, m16 = mq * 4 + mloc;
                const short8* ah = (const short8*)hiH + (size_t)m16 * 32 * 64 + lane;
                const short8* al = (const short8*)hiL + (size_t)m16 * 32 * 64 + lane;
                const short8* gxh = (const short8*)A.gxHi + (size_t)m16 * 48 * 64 + lane;
                const short8* gxl = (const short8*)A.gxLo + (size_t)m16 * 48 * 64 + lane;
                const short8 *whA, *wlA, *whB, *wlB;
                if (gate == 0) {
                    whA = A.dWrH + (size_t)gq * 80 * 64 + lane; wlA = A.dWrL + (size_t)gq * 80 * 64 + lane;
                    whB = whA + 32 * 64; wlB = wlA + 32 * 64;
                } else if (gate == 1) {
                    whA = A.dWzH + (size_t)gq * 80 * 64 + lane; wlA = A.dWzL + (size_t)gq * 80 * 64 + lane;
                    whB = whA + 32 * 64; wlB = wlA + 32 * 64;
                } else {
                    whA = A.dWnhH + (size_t)gq * 32 * 64 + lane; wlA = A.dWnhL + (size_t)gq * 32 * 64 + lane;
                    whB = A.dWniH + (size_t)gq * 48 * 64 + lane; wlB = A.dWniL + (size_t)gq * 48 * 64 + lane;
                }
                f32x4 accA = {0,0,0,0}, accB = {0,0,0,0};
                for (int kt = 0; kt < 32; kt++) {
                    size_t o = (size_t)kt * 64;
                    short8 AH = ah[o], AL = al[o];
                    short8 WH = whA[o], WL = wlA[o];
                    MFMA(accA, AH, WH);
                    MFMA(accA, AH, WL);
                    MFMA(accA, AL, WH);
                }
                for (int kt = 0; kt < 48; kt++) {
                    size_t o = (size_t)kt * 64;
                    short8 AH = gxh[o], AL = gxl[o];
                    short8 WH = whB[o], WL = wlB[o];
                    MFMA(accB, AH, WH);
                    MFMA(accB, AH, WL);
                    MFMA(accB, AL, WH);
                }
                int rsub = (lane >> 4) << 2, cn = lane & 15;
                if (gate < 2) {
#pragma unroll
                    for (int j = 0; j < 4; j++) sm.g.sC[mloc][gate][rsub + j][cn] = accA[j] + accB[j];
                } else {
#pragma unroll
                    for (int j = 0; j < 4; j++) {
                        sm.g.sC[mloc][2][rsub + j][cn] = accA[j];  // nh
                        sm.g.sC[mloc][3][rsub + j][cn] = accB[j];  // ni
                    }
                }
            }
            __syncthreads();
            if (w < 4) {
                int m16 = mq * 4 + w;
                int cu = gq * 16 + (lane & 15);
                int rsub = (lane >> 4) << 2;
                float b_r = A.bih[cu] + A.bhh[cu];
                float b_z = A.bih[UDIM + cu] + A.bhh[UDIM + cu];
                float b_nh = A.bhh[2 * UDIM + cu];
                float b_ni = A.bih[2 * UDIM + cu];
#pragma unroll
                for (int j = 0; j < 4; j++) {
                    int rr = rsub + j, cc = lane & 15;
                    int b = m16 * 16 + rr;
                    float rg = sigm(sm.g.sC[w][0][rr][cc] + b_r);
                    float zg = sigm(sm.g.sC[w][1][rr][cc] + b_z);
                    float nn = tanhf(sm.g.sC[w][3][rr][cc] + b_ni +
                                     rg * (sm.g.sC[w][2][rr][cc] + b_nh));
                    float hp = hinF[(size_t)b * UDIM + cu];
                    float hv = (1.f - zg) * nn + zg * hp;
                    houtF[(size_t)b * UDIM + cu] = hv;
                    sm.g.sHo[w][rr][cc] = hv;
                }
            }
            __syncthreads();
            if (w >= 4 && w < 8 && lane < 32) {
                int m16 = mq * 4 + (w - 4);
                int rr = lane >> 1, oct = lane & 1;
                int brow = m16 * 16 + rr;
                int u0 = gq * 16 + oct * 8;
                float v[8];
#pragma unroll
                for (int j = 0; j < 8; j++) v[j] = sm.g.sHo[w - 4][rr][oct * 8 + j];
                writeSplit8(hoH, hoL, pkChunk(brow, u0, UDIM), v);
            }
        }
        __threadfence();
        grid.sync();

        // ============ Phase F: W2 -> tmp2 (all blocks) + fc/argmax (bid<16) ===
        {
            if (w < 4) {
                int m16 = mq * 4 + w;
                const short8* ah = (const short8*)hoH + (size_t)m16 * 32 * 64 + lane;
                const short8* al = (const short8*)hoL + (size_t)m16 * 32 * 64 + lane;
                const short8* wh = A.w2H + (size_t)gq * 32 * 64 + lane;
                const short8* wl = A.w2L + (size_t)gq * 32 * 64 + lane;
                f32x4 a0 = {0,0,0,0};
                for (int kt = 0; kt < 32; kt++) {
                    size_t o = (size_t)kt * 64;
                    short8 AH = ah[o], AL = al[o];
                    short8 WH = wh[o], WL = wl[o];
                    MFMA(a0, AH, WH);
                    MFMA(a0, AH, WL);
                    MFMA(a0, AL, WH);
                }
                int rsub = (lane >> 4) << 2, cn = lane & 15;
                float bb = A.W2_b[gq * 16 + cn];
#pragma unroll
                for (int r = 0; r < 4; r++) {
                    int row = m16 * 16 + rsub + r;
                    A.tmp2[(size_t)row * UDIM + gq * 16 + cn] = a0[r] + bb;
                }
            } else if (bid < 16 && w < 8) {
                int wv = w - 4;
                const short8* ah = (const short8*)hoH + (size_t)bid * 32 * 64 + lane;
                const short8* al = (const short8*)hoL + (size_t)bid * 32 * 64 + lane;
                int n0 = 2 * wv, n1 = 2 * wv + 1;
                const short8* w0h = A.fcH + (size_t)n0 * 32 * 64 + lane;
                const short8* w0l = A.fcL + (size_t)n0 * 32 * 64 + lane;
                const short8* w1h = A.fcH + (size_t)n1 * 32 * 64 + lane;
                const short8* w1l = A.fcL + (size_t)n1 * 32 * 64 + lane;
                f32x4 a0 = {0,0,0,0}, a1 = {0,0,0,0};
                for (int kt = 0; kt < 32; kt++) {
                    size_t o = (size_t)kt * 64;
                    short8 AH = ah[o], AL = al[o];
                    short8 W0H = w0h[o], W0L = w0l[o], W1H = w1h[o], W1L = w1l[o];
                    MFMA(a0, AH, W0H); MFMA(a1, AH, W1H);
                    MFMA(a0, AH, W0L); MFMA(a1, AH, W1L);
                    MFMA(a0, AL, W0H); MFMA(a1, AL, W1H);
                }
                int cn = lane & 15, rsub = (lane >> 4) << 2;
#pragma unroll
                for (int j = 0; j < 4; j++) {
                    sm.f.sP[rsub + j][n0 * 16 + cn] = a0[j] + A.fc_b[n0 * 16 + cn];
                    sm.f.sP[rsub + j][n1 * 16 + cn] = a1[j] + A.fc_b[n1 * 16 + cn];
                }
            }
            __syncthreads();
            if (bid < 16) {
                if (tid < 256) {
                    int row = tid >> 4, c0 = (tid & 15) * 8;
                    float* pr = A.out + (size_t)(1 + st) * BATCH * VOUTD +
                                (size_t)(bid * 16 + row) * VOUTD;
#pragma unroll
                    for (int j = 0; j < 8; j++) pr[c0 + j] = sm.f.sP[row][c0 + j];
                }
                if (tid < 128) {
                    // 8 lanes per row, first-max semantics
                    int row = tid >> 3, seg = tid & 7;
                    float v = -1e30f;
                    int bi = 0;
                    int c0 = seg * 16;
                    for (int j = c0; j < c0 + 16; j++) {
                        float wv = sm.f.sP[row][j];
                        if (wv > v) { v = wv; bi = j; }
                    }
#pragma unroll
                    for (int off = 1; off < 8; off <<= 1) {
                        float ov = __shfl_xor(v, off);
                        int obi = __shfl_xor(bi, off);
                        if (ov > v || (ov == v && obi < bi)) { v = ov; bi = obi; }
                    }
                    if (seg == 0) A.idx[bid * 16 + row] = bi;
                }
            }
        }
        __threadfence();
        grid.sync();
    }
}

// ---------------------------------------------------------------------------
extern "C" void kernel_launch(void* const* d_in, const int* in_sizes, int n_in,
                              void* d_out, int out_size, void* d_ws, size_t ws_size,
                              hipStream_t stream) {
    const float* x       = (const float*)d_in[0];
    const int*   x_len   = (const int*)d_in[1];
    const float* enc_Wih = (const float*)d_in[2];
    const float* enc_Whh = (const float*)d_in[3];
    const float* enc_bih = (const float*)d_in[4];
    const float* enc_bhh = (const float*)d_in[5];
    const float* dec_Wih = (const float*)d_in[6];
    const float* dec_Whh = (const float*)d_in[7];
    const float* dec_bih = (const float*)d_in[8];
    const float* dec_bhh = (const float*)d_in[9];
    const float* o2h_W   = (const float*)d_in[10];
    const float* o2h_b   = (const float*)d_in[11];
    const float* fc_W    = (const float*)d_in[12];
    const float* fc_b    = (const float*)d_in[13];
    const float* W1_W    = (const float*)d_in[14];
    const float* W1_b    = (const float*)d_in[15];
    const float* W2_W    = (const float*)d_in[16];
    const float* W2_b    = (const float*)d_in[17];
    const float* V_W     = (const float*)d_in[18];
    const float* V_b     = (const float*)d_in[19];
    float* out = (float*)d_out;

    char* p = (char*)d_ws;
    auto alloc = [&](size_t bytes) -> char* {
        char* q = p;
        p += (bytes + 255) & ~(size_t)255;
        return q;
    };
    float* hAF  = (float*)alloc((size_t)BATCH * UDIM * 4);
    float* hBF  = (float*)alloc((size_t)BATCH * UDIM * 4);
    short* hAH  = (short*)alloc((size_t)BATCH * UDIM * 2);
    short* hAL  = (short*)alloc((size_t)BATCH * UDIM * 2);
    short* hBH  = (short*)alloc((size_t)BATCH * UDIM * 2);
    short* hBL  = (short*)alloc((size_t)BATCH * UDIM * 2);
    float* tmp2 = (float*)alloc((size_t)BATCH * UDIM * 4);
    short* gxHi = (short*)alloc((size_t)BATCH * GXW * 2);
    short* gxLo = (short*)alloc((size_t)BATCH * GXW * 2);
    short* encAHi = (short*)alloc((size_t)BATCH * SLEN * UDIM * 2);
    short* encALo = (short*)alloc((size_t)BATCH * SLEN * UDIM * 2);
    float* encProjF = (float*)alloc((size_t)BATCH * SLEN * UDIM * 4);
    float* gihBuf = (float*)alloc((size_t)8 * BATCH * U3 * 4);
    short* eWihH = (short*)alloc((size_t)U3 * VIND * 2);
    short* eWihL = (short*)alloc((size_t)U3 * VIND * 2);
    short* eWrH = (short*)alloc((size_t)UDIM * UDIM * 2);
    short* eWrL = (short*)alloc((size_t)UDIM * UDIM * 2);
    short* eWzH = (short*)alloc((size_t)UDIM * UDIM * 2);
    short* eWzL = (short*)alloc((size_t)UDIM * UDIM * 2);
    short* eWnH = (short*)alloc((size_t)UDIM * UDIM * 2);
    short* eWnL = (short*)alloc((size_t)UDIM * UDIM * 2);
    short* dWrH = (short*)alloc((size_t)UDIM * 2560 * 2);
    short* dWrL = (short*)alloc((size_t)UDIM * 2560 * 2);
    short* dWzH = (short*)alloc((size_t)UDIM * 2560 * 2);
    short* dWzL = (short*)alloc((size_t)UDIM * 2560 * 2);
    short* dWnhH = (short*)alloc((size_t)UDIM * UDIM * 2);
    short* dWnhL = (short*)alloc((size_t)UDIM * UDIM * 2);
    short* dWniH = (short*)alloc((size_t)UDIM * GXW * 2);
    short* dWniL = (short*)alloc((size_t)UDIM * GXW * 2);
    short* w1Hi = (short*)alloc((size_t)UDIM * UDIM * 2);
    short* w1Lo = (short*)alloc((size_t)UDIM * UDIM * 2);
    short* w2Hi = (short*)alloc((size_t)UDIM * UDIM * 2);
    short* w2Lo = (short*)alloc((size_t)UDIM * UDIM * 2);
    short* fcHi = (short*)alloc((size_t)VOUTD * UDIM * 2);
    short* fcLo = (short*)alloc((size_t)VOUTD * UDIM * 2);
    short* xHi  = (short*)alloc((size_t)SLEN * BATCH * VIND * 2);
    short* xLo  = (short*)alloc((size_t)SLEN * BATCH * VIND * 2);
    int*   idx  = (int*)alloc(BATCH * 4);
    float* o2hT = (float*)alloc((size_t)VOUTD * EDIM * 4);

    init_kernel<<<(BATCH * UDIM + 255) / 256, 256, 0, stream>>>(
        hAF, hAH, hAL, out, idx, o2h_W, o2h_b, o2hT);

    // ---- single packing kernel for all weights + x ----
    {
        PackArgs pa;
        int cs = 0, n = 0;
        auto seg = [&](const float* sA, int KA, int offA, const float* sB, int KB,
                       int offB, short* Hi, short* Lo, int R) {
            pa.s[n] = {sA, sB, Hi, Lo, KA, KB, offA, offB, cs};
            cs += R * (KA + KB) / 8;
            n++;
        };
        seg(enc_Wih, VIND, 0, nullptr, 0, 0, eWihH, eWihL, U3);
        seg(enc_Whh, UDIM, 0, nullptr, 0, 0, eWrH, eWrL, UDIM);
        seg(enc_Whh, UDIM, UDIM, nullptr, 0, 0, eWzH, eWzL, UDIM);
        seg(enc_Whh, UDIM, 2 * UDIM, nullptr, 0, 0, eWnH, eWnL, UDIM);
        seg(dec_Whh, UDIM, 0, dec_Wih, GXW, 0, dWrH, dWrL, UDIM);
        seg(dec_Whh, UDIM, UDIM, dec_Wih, GXW, UDIM, dWzH, dWzL, UDIM);
        seg(dec_Whh, UDIM, 2 * UDIM, nullptr, 0, 0, dWnhH, dWnhL, UDIM);
        seg(dec_Wih, GXW, 2 * UDIM, nullptr, 0, 0, dWniH, dWniL, UDIM);
        seg(W1_W, UDIM, 0, nullptr, 0, 0, w1Hi, w1Lo, UDIM);
        seg(W2_W, UDIM, 0, nullptr, 0, 0, w2Hi, w2Lo, UDIM);
        seg(fc_W, UDIM, 0, nullptr, 0, 0, fcHi, fcLo, VOUTD);
        seg(x, VIND, 0, nullptr, 0, 0, xHi, xLo, SLEN * BATCH);
        pack_all<<<(cs + 255) / 256, 256, 0, stream>>>(pa, cs);
    }

    // ---- encoder: 8 chunks of (gi chunk-GEMM + 8 fused GRU steps) ----
    float* hcF = hAF; float* hnF = hBF;
    short *hcH = hAH, *hcL = hAL, *hnH = hBH, *hnL = hBL;
    for (int c = 0; c < 8; c++) {
        gemm_w<<<dim3(32, 24), 256, 0, stream>>>(
            (const short8*)xHi + (size_t)c * 128 * 4 * 64,
            (const short8*)xLo + (size_t)c * 128 * 4 * 64,
            (const short8*)eWihH, (const short8*)eWihL,
            nullptr, gihBuf, VIND / 32, U3);
        for (int tt = 0; tt < 8; tt++) {
            int t = c * 8 + tt;
            enc_gru3<<<dim3(64, 16), 384, 0, stream>>>(
                (const short8*)hcH, (const short8*)hcL,
                (const short8*)eWrH, (const short8*)eWrL,
                (const short8*)eWzH, (const short8*)eWzL,
                (const short8*)eWnH, (const short8*)eWnL,
                gihBuf, enc_bih, enc_bhh, hcF, hnF, hnH, hnL,
                encAHi, encALo, x_len, t);
            { float* tf = hcF; hcF = hnF; hnF = tf; }
            { short* th = hcH; hcH = hnH; hnH = th; th = hcL; hcL = hnL; hnL = th; }
        }
    }

    // ---- enc_proj = enc_out @ W1^T + W1_b (fp32, BN=128 blocks) ----
    gemm_w<<<dim3(SLEN * BATCH / 64, UDIM / 128), 256, 0, stream>>>(
        (const short8*)encAHi, (const short8*)encALo,
        (const short8*)w1Hi, (const short8*)w1Lo,
        W1_b, encProjF, UDIM / 32, UDIM);

    // ---- initial tmp2 from encoder hidden ----
    gemm_bm32<<<dim3(BATCH / 32, UDIM / 64), 256, 0, stream>>>(
        (const short8*)hcH, (const short8*)hcL,
        (const short8*)w2Hi, (const short8*)w2Lo,
        W2_b, tmp2, UDIM / 32, UDIM);

    // ---- greedy decode: ONE persistent cooperative kernel (24 steps) ----
    {
        DecArgs da;
        da.encProj = encProjF;
        da.eaHi = encAHi; da.eaLo = encALo;
        da.tmp2 = tmp2;
        da.V_W = V_W; da.V_b = V_b;
        da.o2hT = o2hT;
        da.idx = idx;
        da.gxHi = gxHi; da.gxLo = gxLo;
        da.dWrH = (const short8*)dWrH; da.dWrL = (const short8*)dWrL;
        da.dWzH = (const short8*)dWzH; da.dWzL = (const short8*)dWzL;
        da.dWnhH = (const short8*)dWnhH; da.dWnhL = (const short8*)dWnhL;
        da.dWniH = (const short8*)dWniH; da.dWniL = (const short8*)dWniL;
        da.bih = dec_bih; da.bhh = dec_bhh;
        da.hAF = hcF; da.hBF = hnF;   // hcF == hAF after even # of swaps
        da.hAH = hcH; da.hAL = hcL; da.hBH = hnH; da.hBL = hnL;
        da.fcH = (const short8*)fcHi; da.fcL = (const short8*)fcLo;
        da.fc_b = fc_b;
        da.w2H = (const short8*)w2Hi; da.w2L = (const short8*)w2Lo;
        da.W2_b = W2_b;
        da.out = out;
        void* kparams[] = { (void*)&da };
        hipLaunchCooperativeKernel(dec_persist, dim3(256), dim3(1024),
                                   kparams, 0u, stream);
    }
}

// Round 4
// 6481.289 us; speedup vs baseline: 1.9943x; 1.9943x over previous
//
#include <hip/hip_runtime.h>
#include <math.h>

#define SLEN 64
#define BATCH 256
#define VIND 128
#define VOUTD 128
#define UDIM 1024
#define EDIM 512
#define TDEC 25
#define U3 3072
#define DECK 2560    // decoder A: [h(1024) | ctx(1024) | emb(512)]
#define NSEG 10

typedef __attribute__((ext_vector_type(8))) short short8;
typedef __attribute__((ext_vector_type(4))) float f32x4;

#define MFMA(acc, A, B) acc = __builtin_amdgcn_mfma_f32_16x16x32_bf16((A), (B), (acc), 0, 0, 0)

// libm sigmoid/tanh in the RECURRENT path (gates): fast variants drift over the
// recurrence and flip greedy argmax (R1 fail).
__device__ __forceinline__ float sigm(float x) { return 1.f / (1.f + expf(-x)); }

// fast tanh for the attention SCORE path only (non-recurrent-critical)
__device__ __forceinline__ float tanhf_fast(float x) {
    float ax = fabsf(x);
    float e = __expf(-2.f * ax);
    float t = (1.f - e) / (1.f + e);
    return copysignf(t, x);
}

__device__ __forceinline__ short f2bf(float f) {
    unsigned u = __float_as_uint(f);
    u += 0x7FFF + ((u >> 16) & 1);
    return (short)(u >> 16);
}
__device__ __forceinline__ float bf2f(short h) {
    return __uint_as_float(((unsigned)(unsigned short)h) << 16);
}

// fragment-major packed layout for operand X[R][K]:
// chunk(r,k) holds X[r][k..k+8); lane = (r&15) + 16*((k>>3)&3)
__device__ __forceinline__ size_t pkChunk(int r, int k, int K) {
    return ((size_t)(r >> 4) * (K >> 5) + (k >> 5)) * 64 + ((r & 15) + 16 * ((k >> 3) & 3));
}

union S8 { short s[8]; short8 v; };

__device__ __forceinline__ void writeSplit8(short* Hi, short* Lo, size_t chunk,
                                            const float* vals) {
    S8 h, l;
#pragma unroll
    for (int j = 0; j < 8; j++) {
        short hb = f2bf(vals[j]);
        h.s[j] = hb;
        l.s[j] = f2bf(vals[j] - bf2f(hb));
    }
    ((short8*)Hi)[chunk] = h.v;
    ((short8*)Lo)[chunk] = l.v;
}

// ---------------------------------------------------------------------------
__global__ void init_kernel(float* __restrict__ h0, short* __restrict__ hpHi,
                            short* __restrict__ hpLo, float* __restrict__ out0,
                            int* __restrict__ idx,
                            const float* __restrict__ o2h_W,
                            const float* __restrict__ o2h_b,
                            float* __restrict__ o2hT) {
    int i = blockIdx.x * 256 + threadIdx.x;
    if (i < BATCH * UDIM) { h0[i] = 0.f; hpHi[i] = 0; hpLo[i] = 0; }
    if (i < BATCH * VOUTD) out0[i] = ((i & (VOUTD - 1)) == 0) ? 1.f : 0.f;
    if (i < BATCH) idx[i] = 0;
    if (i < VOUTD * EDIM) {
        // o2hT[v][e] = o2h_W[e][v] + o2h_b[e]
        int v = i >> 9, e = i & (EDIM - 1);
        o2hT[i] = o2h_W[(size_t)e * VOUTD + v] + o2h_b[e];
    }
}

// ---------------------------------------------------------------------------
// All weight/input packing in ONE kernel: segment table passed by value.
// ---------------------------------------------------------------------------
struct PackSeg {
    const float* sA; const float* sB;
    short* Hi; short* Lo;
    int KA, KB, offA, offB, chunkStart;
};
struct PackArgs { PackSeg s[NSEG]; };

__global__ void pack_all(PackArgs pa, int total) {
    int gid = blockIdx.x * 256 + threadIdx.x;
    if (gid >= total) return;
    int si = 0;
#pragma unroll
    for (int i = 1; i < NSEG; i++) si = (gid >= pa.s[i].chunkStart) ? i : si;
    PackSeg sg = pa.s[si];
    int local = gid - sg.chunkStart;
    int K = sg.KA + sg.KB;
    int cpr = K >> 3;
    int r = local / cpr, k0 = (local - r * cpr) * 8;
    const float* src = (k0 < sg.KA)
        ? sg.sA + (size_t)(sg.offA + r) * sg.KA + k0
        : sg.sB + (size_t)(sg.offB + r) * sg.KB + (k0 - sg.KA);
    float v[8];
#pragma unroll
    for (int j = 0; j < 8; j++) v[j] = src[j];
    writeSplit8(sg.Hi, sg.Lo, pkChunk(r, k0, K), v);
}

// ---------------------------------------------------------------------------
// Split-bf16 3-pass MFMA GEMM, BM=64 x BN=128 block (4 waves of 32x64).
// ---------------------------------------------------------------------------
__global__ __launch_bounds__(256) void gemm_w(
    const short8* __restrict__ Ahi, const short8* __restrict__ Alo,
    const short8* __restrict__ Whi, const short8* __restrict__ Wlo,
    const float* __restrict__ bias, float* __restrict__ C,
    int KT, int N) {
    int tid = threadIdx.x, lane = tid & 63, wave = tid >> 6;
    int m16 = blockIdx.x * 4 + (wave & 1) * 2;
    int nb = blockIdx.y * 8 + (wave >> 1) * 4;
    const short8* a0h = Ahi + (size_t)m16 * KT * 64 + lane;
    const short8* a1h = a0h + (size_t)KT * 64;
    const short8* a0l = Alo + (size_t)m16 * KT * 64 + lane;
    const short8* a1l = a0l + (size_t)KT * 64;
    const short8* w0h = Whi + (size_t)(nb + 0) * KT * 64 + lane;
    const short8* w1h = Whi + (size_t)(nb + 1) * KT * 64 + lane;
    const short8* w2h = Whi + (size_t)(nb + 2) * KT * 64 + lane;
    const short8* w3h = Whi + (size_t)(nb + 3) * KT * 64 + lane;
    const short8* w0l = Wlo + (size_t)(nb + 0) * KT * 64 + lane;
    const short8* w1l = Wlo + (size_t)(nb + 1) * KT * 64 + lane;
    const short8* w2l = Wlo + (size_t)(nb + 2) * KT * 64 + lane;
    const short8* w3l = Wlo + (size_t)(nb + 3) * KT * 64 + lane;
    f32x4 acc0[4] = {}, acc1[4] = {};

    for (int kt = 0; kt < KT; kt++) {
        size_t o = (size_t)kt * 64;
        short8 A0H = a0h[o], A1H = a1h[o], A0L = a0l[o], A1L = a1l[o];
        short8 WH0 = w0h[o], WL0 = w0l[o];
        MFMA(acc0[0], A0H, WH0); MFMA(acc1[0], A1H, WH0);
        MFMA(acc0[0], A0H, WL0); MFMA(acc1[0], A1H, WL0);
        MFMA(acc0[0], A0L, WH0); MFMA(acc1[0], A1L, WH0);
        short8 WH1 = w1h[o], WL1 = w1l[o];
        MFMA(acc0[1], A0H, WH1); MFMA(acc1[1], A1H, WH1);
        MFMA(acc0[1], A0H, WL1); MFMA(acc1[1], A1H, WL1);
        MFMA(acc0[1], A0L, WH1); MFMA(acc1[1], A1L, WH1);
        short8 WH2 = w2h[o], WL2 = w2l[o];
        MFMA(acc0[2], A0H, WH2); MFMA(acc1[2], A1H, WH2);
        MFMA(acc0[2], A0H, WL2); MFMA(acc1[2], A1H, WL2);
        MFMA(acc0[2], A0L, WH2); MFMA(acc1[2], A1L, WH2);
        short8 WH3 = w3h[o], WL3 = w3l[o];
        MFMA(acc0[3], A0H, WH3); MFMA(acc1[3], A1H, WH3);
        MFMA(acc0[3], A0H, WL3); MFMA(acc1[3], A1H, WL3);
        MFMA(acc0[3], A0L, WH3); MFMA(acc1[3], A1L, WH3);
    }
    int rsub = (lane >> 4) * 4, cn = lane & 15;
    int row0 = (m16 + 0) * 16 + rsub;
    int row1 = (m16 + 1) * 16 + rsub;
#pragma unroll
    for (int j = 0; j < 4; j++) {
        int col = (nb + j) * 16 + cn;
        float bb = bias ? bias[col] : 0.f;
#pragma unroll
        for (int r = 0; r < 4; r++) {
            C[(size_t)(row0 + r) * N + col] = acc0[j][r] + bb;
            C[(size_t)(row1 + r) * N + col] = acc1[j][r] + bb;
        }
    }
}

// ---------------------------------------------------------------------------
// BM=32 x BN=64 GEMM (4 waves). Encoder gate GEMM (N=3072) + pre-loop tmp2.
// ---------------------------------------------------------------------------
__global__ __launch_bounds__(256) void gemm_bm32(
    const short8* __restrict__ Ahi, const short8* __restrict__ Alo,
    const short8* __restrict__ Whi, const short8* __restrict__ Wlo,
    const float* __restrict__ bias, float* __restrict__ C,
    int KT, int N) {
    int tid = threadIdx.x, lane = tid & 63, wave = tid >> 6;
    int m16 = blockIdx.x * 2 + (wave & 1);
    int n16 = blockIdx.y * 4 + (wave >> 1) * 2;
    const short8* ah = Ahi + (size_t)m16 * KT * 64 + lane;
    const short8* al = Alo + (size_t)m16 * KT * 64 + lane;
    const short8* w0h = Whi + (size_t)n16 * KT * 64 + lane;
    const short8* w1h = w0h + (size_t)KT * 64;
    const short8* w0l = Wlo + (size_t)n16 * KT * 64 + lane;
    const short8* w1l = w0l + (size_t)KT * 64;
    f32x4 a0 = {0,0,0,0}, a1 = {0,0,0,0};
    for (int kt = 0; kt < KT; kt++) {
        size_t o = (size_t)kt * 64;
        short8 AH = ah[o], AL = al[o];
        short8 W0H = w0h[o], W0L = w0l[o], W1H = w1h[o], W1L = w1l[o];
        MFMA(a0, AH, W0H); MFMA(a1, AH, W1H);
        MFMA(a0, AH, W0L); MFMA(a1, AH, W1L);
        MFMA(a0, AL, W0H); MFMA(a1, AL, W1H);
    }
    int rsub = (lane >> 4) * 4, cn = lane & 15;
    float b0 = bias ? bias[(n16 + 0) * 16 + cn] : 0.f;
    float b1 = bias ? bias[(n16 + 1) * 16 + cn] : 0.f;
#pragma unroll
    for (int r = 0; r < 4; r++) {
        int row = m16 * 16 + rsub + r;
        C[(size_t)row * N + (n16 + 0) * 16 + cn] = a0[r] + b0;
        C[(size_t)row * N + (n16 + 1) * 16 + cn] = a1[r] + b1;
    }
}

// ---------------------------------------------------------------------------
// Decoder gate GEMM: A = hgx packed [256][2560], out gh [256][4096] regions
// [r | z | nh | ni]; K per region: r/z=2560, nh=1024(h), ni=1536(gx).
// Grid (8, 64) = 512 blocks, BM=32 x BN=64.
// ---------------------------------------------------------------------------
__global__ __launch_bounds__(256) void gemm_dec(
    const short8* __restrict__ Ahi, const short8* __restrict__ Alo,
    const short8* __restrict__ WrH, const short8* __restrict__ WrL,
    const short8* __restrict__ WzH, const short8* __restrict__ WzL,
    const short8* __restrict__ WnhH, const short8* __restrict__ WnhL,
    const short8* __restrict__ WniH, const short8* __restrict__ WniL,
    float* __restrict__ gh) {
    int tid = threadIdx.x, lane = tid & 63, wave = tid >> 6;
    int m16 = blockIdx.x * 2 + (wave & 1);
    int by = blockIdx.y;                 // 0..63
    int reg = by >> 4;                   // 0=r 1=z 2=nh 3=ni
    int KT = (reg < 2) ? 80 : (reg == 2 ? 32 : 48);
    int aoff = (reg == 3) ? 32 : 0;      // ni consumes gx part only
    const short8 *BH, *BL;
    if (reg == 0) { BH = WrH; BL = WrL; }
    else if (reg == 1) { BH = WzH; BL = WzL; }
    else if (reg == 2) { BH = WnhH; BL = WnhL; }
    else { BH = WniH; BL = WniL; }
    int nloc = (by & 15) * 4 + (wave >> 1) * 2;   // 0..63 within region
    const short8* ah = Ahi + (size_t)m16 * 80 * 64 + (size_t)aoff * 64 + lane;
    const short8* al = Alo + (size_t)m16 * 80 * 64 + (size_t)aoff * 64 + lane;
    const short8* w0h = BH + (size_t)nloc * KT * 64 + lane;
    const short8* w1h = w0h + (size_t)KT * 64;
    const short8* w0l = BL + (size_t)nloc * KT * 64 + lane;
    const short8* w1l = w0l + (size_t)KT * 64;
    f32x4 a0 = {0,0,0,0}, a1 = {0,0,0,0};
    for (int kt = 0; kt < KT; kt++) {
        size_t o = (size_t)kt * 64;
        short8 AH = ah[o], AL = al[o];
        short8 W0H = w0h[o], W0L = w0l[o], W1H = w1h[o], W1L = w1l[o];
        MFMA(a0, AH, W0H); MFMA(a1, AH, W1H);
        MFMA(a0, AH, W0L); MFMA(a1, AH, W1L);
        MFMA(a0, AL, W0H); MFMA(a1, AL, W1H);
    }
    int rsub = (lane >> 4) * 4, cn = lane & 15;
    int c0 = (reg * 64 + nloc) * 16 + cn;
#pragma unroll
    for (int r = 0; r < 4; r++) {
        int row = m16 * 16 + rsub + r;
        gh[(size_t)row * 4096 + c0] = a0[r];
        gh[(size_t)row * 4096 + c0 + 16] = a1[r];
    }
}

// ---------------------------------------------------------------------------
// Encoder gate tail: gates + mask + h/ea packing. Grid 128 x 256 threads.
// ---------------------------------------------------------------------------
__global__ __launch_bounds__(256) void enc_tail(
    const float* __restrict__ gh,      // [256][3072]
    const float* __restrict__ gi,      // [8*256][3072] chunk buffer
    const float* __restrict__ bih, const float* __restrict__ bhh,
    const float* __restrict__ hinF, float* __restrict__ houtF,
    short* __restrict__ hoH, short* __restrict__ hoL,
    short* __restrict__ eaHi, short* __restrict__ eaLo,
    short* __restrict__ hgxH, short* __restrict__ hgxL,   // K=2560 pack (t==63)
    const int* __restrict__ x_len, int t) {
    int row = blockIdx.x * 2 + (threadIdx.x >> 7);
    int u0 = (threadIdx.x & 127) * 8;
    const float* g = gh + (size_t)row * U3;
    const float* gr = gi + (size_t)((t & 7) * 256 + row) * U3;
    bool msk = t < x_len[row];
    float ho[8], eo[8];
#pragma unroll
    for (int j = 0; j < 8; j++) {
        int u = u0 + j;
        float rg = sigm(g[u] + gr[u] + bih[u] + bhh[u]);
        float zg = sigm(g[UDIM + u] + gr[UDIM + u] + bih[UDIM + u] + bhh[UDIM + u]);
        float nn = tanhf(gr[2 * UDIM + u] + bih[2 * UDIM + u] +
                         rg * (g[2 * UDIM + u] + bhh[2 * UDIM + u]));
        float hp = hinF[(size_t)row * UDIM + u];
        float hv = (1.f - zg) * nn + zg * hp;
        ho[j] = msk ? hv : hp;
        eo[j] = msk ? hv : 0.f;
        houtF[(size_t)row * UDIM + u] = ho[j];
    }
    writeSplit8(hoH, hoL, pkChunk(row, u0, UDIM), ho);
    writeSplit8(eaHi, eaLo, pkChunk(row * SLEN + t, u0, UDIM), eo);
    if (hgxH) writeSplit8(hgxH, hgxL, pkChunk(row, u0, DECK), ho);
}

// ---------------------------------------------------------------------------
// Decoder gate tail: gates + pack h' into next hgx buffer. Grid 128 x 256.
// ---------------------------------------------------------------------------
__global__ __launch_bounds__(256) void dec_tail(
    const float* __restrict__ gh,      // [256][4096] = [r|z|nh|ni]
    const float* __restrict__ bih, const float* __restrict__ bhh,
    const float* __restrict__ hinF, float* __restrict__ houtF,
    short* __restrict__ hgxH, short* __restrict__ hgxL) {
    int row = blockIdx.x * 2 + (threadIdx.x >> 7);
    int u0 = (threadIdx.x & 127) * 8;
    const float* g = gh + (size_t)row * 4096;
    float ho[8];
#pragma unroll
    for (int j = 0; j < 8; j++) {
        int u = u0 + j;
        float rg = sigm(g[u] + bih[u] + bhh[u]);
        float zg = sigm(g[1024 + u] + bih[UDIM + u] + bhh[UDIM + u]);
        float nn = tanhf(g[3072 + u] + bih[2 * UDIM + u] +
                         rg * (g[2048 + u] + bhh[2 * UDIM + u]));
        float hp = hinF[(size_t)row * UDIM + u];
        float hv = (1.f - zg) * nn + zg * hp;
        ho[j] = hv;
        houtF[(size_t)row * UDIM + u] = hv;
    }
    writeSplit8(hgxH, hgxL, pkChunk(row, u0, DECK), ho);
}

// ---------------------------------------------------------------------------
// Attention + ctx + emb -> gx region (k in [1024,2560)) of hgx buffer.
// ---------------------------------------------------------------------------
__global__ __launch_bounds__(1024) void attn_ctx(
    const float* __restrict__ encProj,
    const short* __restrict__ eaHi, const short* __restrict__ eaLo,
    const float* __restrict__ tmp2, const float* __restrict__ V_W,
    const float* __restrict__ V_b,
    const float* __restrict__ o2hT,
    const int* __restrict__ idx, short* __restrict__ gxHi, short* __restrict__ gxLo) {
    int b = blockIdx.x;
    int tid = threadIdx.x, lane = tid & 63, wave = tid >> 6;
    __shared__ float s_t2[UDIM];
    __shared__ float s_v[UDIM];
    __shared__ float s_attn[SLEN];
    __shared__ float s_part[7][128][9];
    for (int u = tid; u < UDIM; u += 1024) {
        s_t2[u] = tmp2[(size_t)b * UDIM + u];
        s_v[u] = V_W[u];
    }
    __syncthreads();
    for (int s = wave; s < SLEN; s += 16) {
        const float4* ep4 = (const float4*)(encProj + ((size_t)b * SLEN + s) * UDIM);
        float p = 0.f;
        for (int u4 = lane; u4 < UDIM / 4; u4 += 64) {
            float4 e = ep4[u4];
            int u = 4 * u4;
            p += tanhf_fast(e.x + s_t2[u]) * s_v[u] +
                 tanhf_fast(e.y + s_t2[u + 1]) * s_v[u + 1] +
                 tanhf_fast(e.z + s_t2[u + 2]) * s_v[u + 2] +
                 tanhf_fast(e.w + s_t2[u + 3]) * s_v[u + 3];
        }
#pragma unroll
        for (int off = 32; off > 0; off >>= 1) p += __shfl_xor(p, off);
        if (lane == 0) s_attn[s] = p + V_b[0];
    }
    __syncthreads();
    if (tid < 64) {
        float v = s_attn[tid];
        float mx = v;
#pragma unroll
        for (int off = 32; off > 0; off >>= 1) mx = fmaxf(mx, __shfl_xor(mx, off));
        float e = expf(v - mx);
        float sum = e;
#pragma unroll
        for (int off = 32; off > 0; off >>= 1) sum += __shfl_xor(sum, off);
        s_attn[tid] = e / sum;
    }
    __syncthreads();
    {
        int grp = tid >> 7, tu = tid & 127;
        int u0 = tu * 8;
        float a[8] = {0, 0, 0, 0, 0, 0, 0, 0};
        const short8* hi8 = (const short8*)eaHi;
        const short8* lo8 = (const short8*)eaLo;
        int lanePart = 16 * ((u0 >> 3) & 3);
        int colPart = u0 >> 5;
        for (int s = grp * 8; s < grp * 8 + 8; s++) {
            int r = b * SLEN + s;
            size_t ch = ((size_t)(r >> 4) * (UDIM >> 5) + colPart) * 64 + (r & 15) + lanePart;
            S8 h, l;
            h.v = hi8[ch];
            l.v = lo8[ch];
            float wt = s_attn[s];
#pragma unroll
            for (int j = 0; j < 8; j++) a[j] += wt * (bf2f(h.s[j]) + bf2f(l.s[j]));
        }
        if (grp) {
#pragma unroll
            for (int j = 0; j < 8; j++) s_part[grp - 1][tu][j] = a[j];
        }
        __syncthreads();
        if (tid < 128) {
#pragma unroll
            for (int gg = 0; gg < 7; gg++)
#pragma unroll
                for (int j = 0; j < 8; j++) a[j] += s_part[gg][tu][j];
            writeSplit8(gxHi, gxLo, pkChunk(b, 1024 + u0, DECK), a);
        } else if (tid < 192) {
            int e0 = (tid - 128) * 8;
            int ib = idx[b];
            const float* row = o2hT + (size_t)ib * EDIM + e0;
            float v[8];
#pragma unroll
            for (int j = 0; j < 8; j++) v[j] = row[j];
            writeSplit8(gxHi, gxLo, pkChunk(b, 2048 + e0, DECK), v);
        }
    }
}

// ---------------------------------------------------------------------------
// Merged: pred=h@fc^T+b + parallel argmax (blocks 0..15) AND tmp2=h@W2^T+b
// (blocks 16..143). A = hgx packed (K=2560 layout, h region = kt 0..31).
// ---------------------------------------------------------------------------
__global__ __launch_bounds__(256) void fcw2(
    const short8* __restrict__ hHi, const short8* __restrict__ hLo,
    const short8* __restrict__ fcH, const short8* __restrict__ fcL,
    const float* __restrict__ fc_b, float* __restrict__ pred,
    int* __restrict__ idx,
    const short8* __restrict__ w2H, const short8* __restrict__ w2L,
    const float* __restrict__ W2_b, float* __restrict__ tmp2) {
    __shared__ float sP[16][129];
    int tid = threadIdx.x, lane = tid & 63, wave = tid >> 6;
    if (blockIdx.x < 16) {
        int fm = blockIdx.x;
        const short8* ah = hHi + (size_t)fm * 80 * 64 + lane;
        const short8* al = hLo + (size_t)fm * 80 * 64 + lane;
        int n0 = 2 * wave, n1 = 2 * wave + 1;
        const short8* w0h = fcH + (size_t)n0 * 32 * 64 + lane;
        const short8* w0l = fcL + (size_t)n0 * 32 * 64 + lane;
        const short8* w1h = fcH + (size_t)n1 * 32 * 64 + lane;
        const short8* w1l = fcL + (size_t)n1 * 32 * 64 + lane;
        f32x4 a0 = {0,0,0,0}, a1 = {0,0,0,0};
        for (int kt = 0; kt < 32; kt++) {
            size_t o = (size_t)kt * 64;
            short8 AH = ah[o], AL = al[o];
            short8 W0H = w0h[o], W0L = w0l[o], W1H = w1h[o], W1L = w1l[o];
            MFMA(a0, AH, W0H); MFMA(a1, AH, W1H);
            MFMA(a0, AH, W0L); MFMA(a1, AH, W1L);
            MFMA(a0, AL, W0H); MFMA(a1, AL, W1H);
        }
        int cn = lane & 15, rsub = (lane >> 4) << 2;
#pragma unroll
        for (int j = 0; j < 4; j++) {
            sP[rsub + j][n0 * 16 + cn] = a0[j] + fc_b[n0 * 16 + cn];
            sP[rsub + j][n1 * 16 + cn] = a1[j] + fc_b[n1 * 16 + cn];
        }
        __syncthreads();
        {
            int row = tid >> 4, c0 = (tid & 15) * 8;
            float* pr = pred + (size_t)(fm * 16 + row) * VOUTD;
#pragma unroll
            for (int j = 0; j < 8; j++) pr[c0 + j] = sP[row][c0 + j];
        }
        if (tid < 128) {
            int row = tid >> 3, seg = tid & 7;
            float v = -1e30f;
            int bi = 0;
            int c0 = seg * 16;
            for (int j = c0; j < c0 + 16; j++) {
                float w = sP[row][j];
                if (w > v) { v = w; bi = j; }
            }
#pragma unroll
            for (int off = 1; off < 8; off <<= 1) {
                float ov = __shfl_xor(v, off);
                int obi = __shfl_xor(bi, off);
                if (ov > v || (ov == v && obi < bi)) { v = ov; bi = obi; }
            }
            if (seg == 0) idx[fm * 16 + row] = bi;
        }
    } else {
        int lin = blockIdx.x - 16;       // 0..127
        int bx = lin & 7, by = lin >> 3; // bm32 grid (8, 16)
        int m16 = bx * 2 + (wave & 1);
        int n16 = by * 4 + (wave >> 1) * 2;
        const short8* ah = hHi + (size_t)m16 * 80 * 64 + lane;
        const short8* al = hLo + (size_t)m16 * 80 * 64 + lane;
        const short8* w0h = w2H + (size_t)n16 * 32 * 64 + lane;
        const short8* w1h = w0h + (size_t)32 * 64;
        const short8* w0l = w2L + (size_t)n16 * 32 * 64 + lane;
        const short8* w1l = w0l + (size_t)32 * 64;
        f32x4 a0 = {0,0,0,0}, a1 = {0,0,0,0};
        for (int kt = 0; kt < 32; kt++) {
            size_t o = (size_t)kt * 64;
            short8 AH = ah[o], AL = al[o];
            short8 W0H = w0h[o], W0L = w0l[o], W1H = w1h[o], W1L = w1l[o];
            MFMA(a0, AH, W0H); MFMA(a1, AH, W1H);
            MFMA(a0, AH, W0L); MFMA(a1, AH, W1L);
            MFMA(a0, AL, W0H); MFMA(a1, AL, W1H);
        }
        int rsub = (lane >> 4) * 4, cn = lane & 15;
        float b0 = W2_b[(n16 + 0) * 16 + cn];
        float b1 = W2_b[(n16 + 1) * 16 + cn];
#pragma unroll
        for (int r = 0; r < 4; r++) {
            int row = m16 * 16 + rsub + r;
            tmp2[(size_t)row * UDIM + (n16 + 0) * 16 + cn] = a0[r] + b0;
            tmp2[(size_t)row * UDIM + (n16 + 1) * 16 + cn] = a1[r] + b1;
        }
    }
}

// ---------------------------------------------------------------------------
extern "C" void kernel_launch(void* const* d_in, const int* in_sizes, int n_in,
                              void* d_out, int out_size, void* d_ws, size_t ws_size,
                              hipStream_t stream) {
    const float* x       = (const float*)d_in[0];
    const int*   x_len   = (const int*)d_in[1];
    const float* enc_Wih = (const float*)d_in[2];
    const float* enc_Whh = (const float*)d_in[3];
    const float* enc_bih = (const float*)d_in[4];
    const float* enc_bhh = (const float*)d_in[5];
    const float* dec_Wih = (const float*)d_in[6];
    const float* dec_Whh = (const float*)d_in[7];
    const float* dec_bih = (const float*)d_in[8];
    const float* dec_bhh = (const float*)d_in[9];
    const float* o2h_W   = (const float*)d_in[10];
    const float* o2h_b   = (const float*)d_in[11];
    const float* fc_W    = (const float*)d_in[12];
    const float* fc_b    = (const float*)d_in[13];
    const float* W1_W    = (const float*)d_in[14];
    const float* W1_b    = (const float*)d_in[15];
    const float* W2_W    = (const float*)d_in[16];
    const float* W2_b    = (const float*)d_in[17];
    const float* V_W     = (const float*)d_in[18];
    const float* V_b     = (const float*)d_in[19];
    float* out = (float*)d_out;

    char* p = (char*)d_ws;
    auto alloc = [&](size_t bytes) -> char* {
        char* q = p;
        p += (bytes + 255) & ~(size_t)255;
        return q;
    };
    float* hAF  = (float*)alloc((size_t)BATCH * UDIM * 4);
    float* hBF  = (float*)alloc((size_t)BATCH * UDIM * 4);
    short* hAH  = (short*)alloc((size_t)BATCH * UDIM * 2);
    short* hAL  = (short*)alloc((size_t)BATCH * UDIM * 2);
    short* hBH  = (short*)alloc((size_t)BATCH * UDIM * 2);
    short* hBL  = (short*)alloc((size_t)BATCH * UDIM * 2);
    float* tmp2 = (float*)alloc((size_t)BATCH * UDIM * 4);
    short* hgxAH = (short*)alloc((size_t)BATCH * DECK * 2);
    short* hgxAL = (short*)alloc((size_t)BATCH * DECK * 2);
    short* hgxBH = (short*)alloc((size_t)BATCH * DECK * 2);
    short* hgxBL = (short*)alloc((size_t)BATCH * DECK * 2);
    float* ghEnc = (float*)alloc((size_t)BATCH * U3 * 4);
    float* ghDec = (float*)alloc((size_t)BATCH * 4096 * 4);
    short* encAHi = (short*)alloc((size_t)BATCH * SLEN * UDIM * 2);
    short* encALo = (short*)alloc((size_t)BATCH * SLEN * UDIM * 2);
    float* encProjF = (float*)alloc((size_t)BATCH * SLEN * UDIM * 4);
    float* gihBuf = (float*)alloc((size_t)8 * BATCH * U3 * 4);
    short* eWihH = (short*)alloc((size_t)U3 * VIND * 2);
    short* eWihL = (short*)alloc((size_t)U3 * VIND * 2);
    short* eWhhH = (short*)alloc((size_t)U3 * UDIM * 2);
    short* eWhhL = (short*)alloc((size_t)U3 * UDIM * 2);
    short* dWrH = (short*)alloc((size_t)UDIM * DECK * 2);
    short* dWrL = (short*)alloc((size_t)UDIM * DECK * 2);
    short* dWzH = (short*)alloc((size_t)UDIM * DECK * 2);
    short* dWzL = (short*)alloc((size_t)UDIM * DECK * 2);
    short* dWnhH = (short*)alloc((size_t)UDIM * UDIM * 2);
    short* dWnhL = (short*)alloc((size_t)UDIM * UDIM * 2);
    short* dWniH = (short*)alloc((size_t)UDIM * 1536 * 2);
    short* dWniL = (short*)alloc((size_t)UDIM * 1536 * 2);
    short* w1Hi = (short*)alloc((size_t)UDIM * UDIM * 2);
    short* w1Lo = (short*)alloc((size_t)UDIM * UDIM * 2);
    short* w2Hi = (short*)alloc((size_t)UDIM * UDIM * 2);
    short* w2Lo = (short*)alloc((size_t)UDIM * UDIM * 2);
    short* fcHi = (short*)alloc((size_t)VOUTD * UDIM * 2);
    short* fcLo = (short*)alloc((size_t)VOUTD * UDIM * 2);
    short* xHi  = (short*)alloc((size_t)SLEN * BATCH * VIND * 2);
    short* xLo  = (short*)alloc((size_t)SLEN * BATCH * VIND * 2);
    int*   idx  = (int*)alloc(BATCH * 4);
    float* o2hT = (float*)alloc((size_t)VOUTD * EDIM * 4);

    init_kernel<<<(BATCH * UDIM + 255) / 256, 256, 0, stream>>>(
        hAF, hAH, hAL, out, idx, o2h_W, o2h_b, o2hT);

    // ---- single packing kernel for all weights + x ----
    {
        PackArgs pa;
        int cs = 0, n = 0;
        auto seg = [&](const float* sA, int KA, int offA, const float* sB, int KB,
                       int offB, short* Hi, short* Lo, int R) {
            pa.s[n] = {sA, sB, Hi, Lo, KA, KB, offA, offB, cs};
            cs += R * (KA + KB) / 8;
            n++;
        };
        seg(enc_Wih, VIND, 0, nullptr, 0, 0, eWihH, eWihL, U3);
        seg(enc_Whh, UDIM, 0, nullptr, 0, 0, eWhhH, eWhhL, U3);
        seg(dec_Whh, UDIM, 0, dec_Wih, 1536, 0, dWrH, dWrL, UDIM);
        seg(dec_Whh, UDIM, UDIM, dec_Wih, 1536, UDIM, dWzH, dWzL, UDIM);
        seg(dec_Whh, UDIM, 2 * UDIM, nullptr, 0, 0, dWnhH, dWnhL, UDIM);
        seg(dec_Wih, 1536, 2 * UDIM, nullptr, 0, 0, dWniH, dWniL, UDIM);
        seg(W1_W, UDIM, 0, nullptr, 0, 0, w1Hi, w1Lo, UDIM);
        seg(W2_W, UDIM, 0, nullptr, 0, 0, w2Hi, w2Lo, UDIM);
        seg(fc_W, UDIM, 0, nullptr, 0, 0, fcHi, fcLo, VOUTD);
        seg(x, VIND, 0, nullptr, 0, 0, xHi, xLo, SLEN * BATCH);
        pack_all<<<(cs + 255) / 256, 256, 0, stream>>>(pa, cs);
    }

    // ---- encoder: 8 chunks of (gi chunk-GEMM + 8x [gate GEMM + tail]) ----
    float* hcF = hAF; float* hnF = hBF;
    short *hcH = hAH, *hcL = hAL, *hnH = hBH, *hnL = hBL;
    for (int c = 0; c < 8; c++) {
        gemm_w<<<dim3(32, 24), 256, 0, stream>>>(
            (const short8*)xHi + (size_t)c * 128 * 4 * 64,
            (const short8*)xLo + (size_t)c * 128 * 4 * 64,
            (const short8*)eWihH, (const short8*)eWihL,
            nullptr, gihBuf, VIND / 32, U3);
        for (int tt = 0; tt < 8; tt++) {
            int t = c * 8 + tt;
            gemm_bm32<<<dim3(8, 48), 256, 0, stream>>>(
                (const short8*)hcH, (const short8*)hcL,
                (const short8*)eWhhH, (const short8*)eWhhL,
                nullptr, ghEnc, 32, U3);
            enc_tail<<<128, 256, 0, stream>>>(
                ghEnc, gihBuf, enc_bih, enc_bhh, hcF, hnF, hnH, hnL,
                encAHi, encALo,
                (t == SLEN - 1) ? hgxAH : (short*)nullptr,
                (t == SLEN - 1) ? hgxAL : (short*)nullptr,
                x_len, t);
            { float* tf = hcF; hcF = hnF; hnF = tf; }
            { short* th = hcH; hcH = hnH; hnH = th; th = hcL; hcL = hnL; hnL = th; }
        }
    }

    // ---- enc_proj = enc_out @ W1^T + W1_b ----
    gemm_w<<<dim3(SLEN * BATCH / 64, UDIM / 128), 256, 0, stream>>>(
        (const short8*)encAHi, (const short8*)encALo,
        (const short8*)w1Hi, (const short8*)w1Lo,
        W1_b, encProjF, UDIM / 32, UDIM);

    // ---- initial tmp2 from encoder hidden (K=1024 pack) ----
    gemm_bm32<<<dim3(BATCH / 32, UDIM / 64), 256, 0, stream>>>(
        (const short8*)hcH, (const short8*)hcL,
        (const short8*)w2Hi, (const short8*)w2Lo,
        W2_b, tmp2, UDIM / 32, UDIM);

    // ---- greedy decode: 24 steps x {attn, gate GEMM, tail, fcw2} ----
    short* hgH[2] = {hgxAH, hgxBH};
    short* hgL[2] = {hgxAL, hgxBL};
    for (int st = 0; st < TDEC - 1; st++) {
        int cur = st & 1, nxt = cur ^ 1;
        attn_ctx<<<BATCH, 1024, 0, stream>>>(
            encProjF, encAHi, encALo, tmp2, V_W, V_b, o2hT, idx,
            hgH[cur], hgL[cur]);
        gemm_dec<<<dim3(8, 64), 256, 0, stream>>>(
            (const short8*)hgH[cur], (const short8*)hgL[cur],
            (const short8*)dWrH, (const short8*)dWrL,
            (const short8*)dWzH, (const short8*)dWzL,
            (const short8*)dWnhH, (const short8*)dWnhL,
            (const short8*)dWniH, (const short8*)dWniL, ghDec);
        dec_tail<<<128, 256, 0, stream>>>(
            ghDec, dec_bih, dec_bhh, hcF, hnF, hgH[nxt], hgL[nxt]);
        float* pred = out + (size_t)(1 + st) * BATCH * VOUTD;
        fcw2<<<144, 256, 0, stream>>>(
            (const short8*)hgH[nxt], (const short8*)hgL[nxt],
            (const short8*)fcHi, (const short8*)fcLo,
            fc_b, pred, idx,
            (const short8*)w2Hi, (const short8*)w2Lo, W2_b, tmp2);
        { float* tf = hcF; hcF = hnF; hnF = tf; }
    }
}

// Round 5
// 3487.439 us; speedup vs baseline: 3.7063x; 1.8585x over previous
//
#include <hip/hip_runtime.h>
#include <math.h>

#define SLEN 64
#define BATCH 256
#define VIND 128
#define VOUTD 128
#define UDIM 1024
#define EDIM 512
#define TDEC 25
#define GXW 1536
#define U3 3072
#define NSEG 12

typedef __attribute__((ext_vector_type(8))) short short8;
typedef __attribute__((ext_vector_type(4))) float f32x4;

#define MFMA(acc, A, B) acc = __builtin_amdgcn_mfma_f32_16x16x32_bf16((A), (B), (acc), 0, 0, 0)

// libm sigmoid/tanh in the RECURRENT path (gates): fast variants drift over the
// 64-step encoder + 24-step decoder recurrence and flip greedy argmax (R1 fail).
__device__ __forceinline__ float sigm(float x) { return 1.f / (1.f + expf(-x)); }

// fast tanh for the attention SCORE path only (non-recurrent-critical)
__device__ __forceinline__ float tanhf_fast(float x) {
    float ax = fabsf(x);
    float e = __expf(-2.f * ax);
    float t = (1.f - e) / (1.f + e);
    return copysignf(t, x);
}

__device__ __forceinline__ short f2bf(float f) {
    unsigned u = __float_as_uint(f);
    u += 0x7FFF + ((u >> 16) & 1);
    return (short)(u >> 16);
}
__device__ __forceinline__ float bf2f(short h) {
    return __uint_as_float(((unsigned)(unsigned short)h) << 16);
}

// fragment-major packed layout for operand X[R][K]:
// chunk(r,k) holds X[r][k..k+8); lane = (r&15) + 16*((k>>3)&3)
__device__ __forceinline__ size_t pkChunk(int r, int k, int K) {
    return ((size_t)(r >> 4) * (K >> 5) + (k >> 5)) * 64 + ((r & 15) + 16 * ((k >> 3) & 3));
}

union S8 { short s[8]; short8 v; };

__device__ __forceinline__ void writeSplit8(short* Hi, short* Lo, size_t chunk,
                                            const float* vals) {
    S8 h, l;
#pragma unroll
    for (int j = 0; j < 8; j++) {
        short hb = f2bf(vals[j]);
        h.s[j] = hb;
        l.s[j] = f2bf(vals[j] - bf2f(hb));
    }
    ((short8*)Hi)[chunk] = h.v;
    ((short8*)Lo)[chunk] = l.v;
}

// ---------------------------------------------------------------------------
__global__ void init_kernel(float* __restrict__ h0, short* __restrict__ hpHi,
                            short* __restrict__ hpLo, float* __restrict__ out0,
                            int* __restrict__ idx,
                            const float* __restrict__ o2h_W,
                            const float* __restrict__ o2h_b,
                            float* __restrict__ o2hT) {
    int i = blockIdx.x * 256 + threadIdx.x;
    if (i < BATCH * UDIM) { h0[i] = 0.f; hpHi[i] = 0; hpLo[i] = 0; }
    if (i < BATCH * VOUTD) out0[i] = ((i & (VOUTD - 1)) == 0) ? 1.f : 0.f;
    if (i < BATCH) idx[i] = 0;
    if (i < VOUTD * EDIM) {
        // o2hT[v][e] = o2h_W[e][v] + o2h_b[e]  (bias folded, row-read at decode)
        int v = i >> 9, e = i & (EDIM - 1);
        o2hT[i] = o2h_W[(size_t)e * VOUTD + v] + o2h_b[e];
    }
}

// ---------------------------------------------------------------------------
// All weight/input packing in ONE kernel: segment table passed by value.
// ---------------------------------------------------------------------------
struct PackSeg {
    const float* sA; const float* sB;
    short* Hi; short* Lo;
    int KA, KB, offA, offB, chunkStart;
};
struct PackArgs { PackSeg s[NSEG]; };

__global__ void pack_all(PackArgs pa, int total) {
    int gid = blockIdx.x * 256 + threadIdx.x;
    if (gid >= total) return;
    int si = 0;
#pragma unroll
    for (int i = 1; i < NSEG; i++) si = (gid >= pa.s[i].chunkStart) ? i : si;
    PackSeg sg = pa.s[si];
    int local = gid - sg.chunkStart;
    int K = sg.KA + sg.KB;
    int cpr = K >> 3;
    int r = local / cpr, k0 = (local - r * cpr) * 8;
    const float* src = (k0 < sg.KA)
        ? sg.sA + (size_t)(sg.offA + r) * sg.KA + k0
        : sg.sB + (size_t)(sg.offB + r) * sg.KB + (k0 - sg.KA);
    float v[8];
#pragma unroll
    for (int j = 0; j < 8; j++) v[j] = src[j];
    writeSplit8(sg.Hi, sg.Lo, pkChunk(r, k0, K), v);
}

// ---------------------------------------------------------------------------
// Split-bf16 3-pass MFMA GEMM, BM=64 x BN=128 block (4 waves of 32x64).
// ---------------------------------------------------------------------------
__global__ __launch_bounds__(256) void gemm_w(
    const short8* __restrict__ Ahi, const short8* __restrict__ Alo,
    const short8* __restrict__ Whi, const short8* __restrict__ Wlo,
    const float* __restrict__ bias, float* __restrict__ C,
    int KT, int N) {
    int tid = threadIdx.x, lane = tid & 63, wave = tid >> 6;
    int m16 = blockIdx.x * 4 + (wave & 1) * 2;
    int nb = blockIdx.y * 8 + (wave >> 1) * 4;
    const short8* a0h = Ahi + (size_t)m16 * KT * 64 + lane;
    const short8* a1h = a0h + (size_t)KT * 64;
    const short8* a0l = Alo + (size_t)m16 * KT * 64 + lane;
    const short8* a1l = a0l + (size_t)KT * 64;
    const short8* w0h = Whi + (size_t)(nb + 0) * KT * 64 + lane;
    const short8* w1h = Whi + (size_t)(nb + 1) * KT * 64 + lane;
    const short8* w2h = Whi + (size_t)(nb + 2) * KT * 64 + lane;
    const short8* w3h = Whi + (size_t)(nb + 3) * KT * 64 + lane;
    const short8* w0l = Wlo + (size_t)(nb + 0) * KT * 64 + lane;
    const short8* w1l = Wlo + (size_t)(nb + 1) * KT * 64 + lane;
    const short8* w2l = Wlo + (size_t)(nb + 2) * KT * 64 + lane;
    const short8* w3l = Wlo + (size_t)(nb + 3) * KT * 64 + lane;
    f32x4 acc0[4] = {}, acc1[4] = {};

    for (int kt = 0; kt < KT; kt++) {
        size_t o = (size_t)kt * 64;
        short8 A0H = a0h[o], A1H = a1h[o], A0L = a0l[o], A1L = a1l[o];
        short8 WH0 = w0h[o], WL0 = w0l[o];
        MFMA(acc0[0], A0H, WH0); MFMA(acc1[0], A1H, WH0);
        MFMA(acc0[0], A0H, WL0); MFMA(acc1[0], A1H, WL0);
        MFMA(acc0[0], A0L, WH0); MFMA(acc1[0], A1L, WH0);
        short8 WH1 = w1h[o], WL1 = w1l[o];
        MFMA(acc0[1], A0H, WH1); MFMA(acc1[1], A1H, WH1);
        MFMA(acc0[1], A0H, WL1); MFMA(acc1[1], A1H, WL1);
        MFMA(acc0[1], A0L, WH1); MFMA(acc1[1], A1L, WH1);
        short8 WH2 = w2h[o], WL2 = w2l[o];
        MFMA(acc0[2], A0H, WH2); MFMA(acc1[2], A1H, WH2);
        MFMA(acc0[2], A0H, WL2); MFMA(acc1[2], A1H, WL2);
        MFMA(acc0[2], A0L, WH2); MFMA(acc1[2], A1L, WH2);
        short8 WH3 = w3h[o], WL3 = w3l[o];
        MFMA(acc0[3], A0H, WH3); MFMA(acc1[3], A1H, WH3);
        MFMA(acc0[3], A0H, WL3); MFMA(acc1[3], A1H, WL3);
        MFMA(acc0[3], A0L, WH3); MFMA(acc1[3], A1L, WH3);
    }
    int rsub = (lane >> 4) * 4, cn = lane & 15;
    int row0 = (m16 + 0) * 16 + rsub;
    int row1 = (m16 + 1) * 16 + rsub;
#pragma unroll
    for (int j = 0; j < 4; j++) {
        int col = (nb + j) * 16 + cn;
        float bb = bias ? bias[col] : 0.f;
#pragma unroll
        for (int r = 0; r < 4; r++) {
            C[(size_t)(row0 + r) * N + col] = acc0[j][r] + bb;
            C[(size_t)(row1 + r) * N + col] = acc1[j][r] + bb;
        }
    }
}

// ---------------------------------------------------------------------------
// BM=32 GEMM for the pre-loop tmp2. Grid (M/32, N/64).
// ---------------------------------------------------------------------------
__global__ __launch_bounds__(256) void gemm_bm32(
    const short8* __restrict__ Ahi, const short8* __restrict__ Alo,
    const short8* __restrict__ Whi, const short8* __restrict__ Wlo,
    const float* __restrict__ bias, float* __restrict__ C,
    int KT, int N) {
    int tid = threadIdx.x, lane = tid & 63, wave = tid >> 6;
    int m16 = blockIdx.x * 2 + (wave & 1);
    int n16 = blockIdx.y * 4 + (wave >> 1) * 2;
    const short8* ah = Ahi + (size_t)m16 * KT * 64 + lane;
    const short8* al = Alo + (size_t)m16 * KT * 64 + lane;
    const short8* w0h = Whi + (size_t)n16 * KT * 64 + lane;
    const short8* w1h = w0h + (size_t)KT * 64;
    const short8* w0l = Wlo + (size_t)n16 * KT * 64 + lane;
    const short8* w1l = w0l + (size_t)KT * 64;
    f32x4 a0 = {0,0,0,0}, a1 = {0,0,0,0};
    for (int kt = 0; kt < KT; kt++) {
        size_t o = (size_t)kt * 64;
        short8 AH = ah[o], AL = al[o];
        short8 W0H = w0h[o], W0L = w0l[o], W1H = w1h[o], W1L = w1l[o];
        MFMA(a0, AH, W0H); MFMA(a1, AH, W1H);
        MFMA(a0, AH, W0L); MFMA(a1, AH, W1L);
        MFMA(a0, AL, W0H); MFMA(a1, AL, W1H);
    }
    int rsub = (lane >> 4) * 4, cn = lane & 15;
    float b0 = bias ? bias[(n16 + 0) * 16 + cn] : 0.f;
    float b1 = bias ? bias[(n16 + 1) * 16 + cn] : 0.f;
#pragma unroll
    for (int r = 0; r < 4; r++) {
        int row = m16 * 16 + rsub + r;
        C[(size_t)row * N + (n16 + 0) * 16 + cn] = a0[r] + b0;
        C[(size_t)row * N + (n16 + 1) * 16 + cn] = a1[r] + b1;
    }
}

// ---------------------------------------------------------------------------
// Encoder GRU step: 6 waves (gate x K-half), each wave covers TWO m16 tiles
// (halves weight re-reads vs R2: 200 -> 100 MB/step). Grid (64, 8).
// Math is bitwise-identical to R2 (same K-split halves, same sum order).
// ---------------------------------------------------------------------------
__global__ __launch_bounds__(384) void enc_gru3(
    const short8* __restrict__ hinH8, const short8* __restrict__ hinL8,
    const short8* __restrict__ WrH, const short8* __restrict__ WrL,
    const short8* __restrict__ WzH, const short8* __restrict__ WzL,
    const short8* __restrict__ WnH, const short8* __restrict__ WnL,
    const float* __restrict__ gi,
    const float* __restrict__ bih, const float* __restrict__ bhh,
    const float* __restrict__ hinF, float* __restrict__ houtF,
    short* __restrict__ hoH, short* __restrict__ hoL,
    short* __restrict__ eaHi, short* __restrict__ eaLo,
    const int* __restrict__ x_len, int t) {
    __shared__ float sC[6][2][16][16];
    __shared__ float sHo[2][16][16];
    __shared__ float sEo[2][16][16];
    int tid = threadIdx.x, lane = tid & 63, wave = tid >> 6;  // wave 0..5
    int g = blockIdx.x;
    int m16a = blockIdx.y * 2;
    int gate = wave >> 1, half = wave & 1;
    const short8* a0h = hinH8 + (size_t)m16a * 32 * 64 + (size_t)half * 16 * 64 + lane;
    const short8* a0l = hinL8 + (size_t)m16a * 32 * 64 + (size_t)half * 16 * 64 + lane;
    const short8* a1h = a0h + (size_t)32 * 64;
    const short8* a1l = a0l + (size_t)32 * 64;
    const short8* WH0 = (gate == 0) ? WrH : (gate == 1) ? WzH : WnH;
    const short8* WL0 = (gate == 0) ? WrL : (gate == 1) ? WzL : WnL;
    const short8* wh = WH0 + (size_t)g * 32 * 64 + (size_t)half * 16 * 64 + lane;
    const short8* wl = WL0 + (size_t)g * 32 * 64 + (size_t)half * 16 * 64 + lane;
    f32x4 acc0 = {0, 0, 0, 0}, acc1 = {0, 0, 0, 0};
    for (int kt = 0; kt < 16; kt++) {
        size_t o = (size_t)kt * 64;
        short8 WH = wh[o], WL = wl[o];
        short8 A0H = a0h[o], A0L = a0l[o];
        MFMA(acc0, A0H, WH); MFMA(acc0, A0H, WL); MFMA(acc0, A0L, WH);
        short8 A1H = a1h[o], A1L = a1l[o];
        MFMA(acc1, A1H, WH); MFMA(acc1, A1H, WL); MFMA(acc1, A1L, WH);
    }
    {
        int rsub = (lane >> 4) << 2, cn = lane & 15;
#pragma unroll
        for (int j = 0; j < 4; j++) {
            sC[wave][0][rsub + j][cn] = acc0[j];
            sC[wave][1][rsub + j][cn] = acc1[j];
        }
    }
    __syncthreads();
    if (wave < 2) {
        int m16 = m16a + wave;
        int cu = g * 16 + (lane & 15);
        int rsub = (lane >> 4) << 2;
        float b_r = bih[cu] + bhh[cu];
        float b_z = bih[UDIM + cu] + bhh[UDIM + cu];
        float b_nh = bhh[2 * UDIM + cu];
        float b_ni = bih[2 * UDIM + cu];
        int growLocal = (t & 7) * 256;
#pragma unroll
        for (int j = 0; j < 4; j++) {
            int rr = rsub + j, cc = lane & 15;
            int b = m16 * 16 + rr;
            const float* gr = gi + (size_t)(growLocal + b) * U3;
            float rg = sigm(sC[0][wave][rr][cc] + sC[1][wave][rr][cc] + gr[cu] + b_r);
            float zg = sigm(sC[2][wave][rr][cc] + sC[3][wave][rr][cc] + gr[UDIM + cu] + b_z);
            float nn = tanhf(gr[2 * UDIM + cu] + b_ni +
                             rg * (sC[4][wave][rr][cc] + sC[5][wave][rr][cc] + b_nh));
            float hp = hinF[(size_t)b * UDIM + cu];
            float hv = (1.f - zg) * nn + zg * hp;
            bool msk = t < x_len[b];
            float ho = msk ? hv : hp;
            houtF[(size_t)b * UDIM + cu] = ho;
            sHo[wave][rr][cc] = ho;
            sEo[wave][rr][cc] = msk ? hv : 0.f;
        }
    }
    __syncthreads();
    if (wave >= 2 && wave < 4 && lane < 32) {
        int tile = wave - 2;
        int m16 = m16a + tile;
        int rr = lane >> 1, oct = lane & 1;
        int brow = m16 * 16 + rr;
        int u0 = g * 16 + oct * 8;
        float v[8];
#pragma unroll
        for (int j = 0; j < 8; j++) v[j] = sHo[tile][rr][oct * 8 + j];
        writeSplit8(hoH, hoL, pkChunk(brow, u0, UDIM), v);
#pragma unroll
        for (int j = 0; j < 8; j++) v[j] = sEo[tile][rr][oct * 8 + j];
        writeSplit8(eaHi, eaLo, pkChunk(brow * SLEN + t, u0, UDIM), v);
    }
}

// ---------------------------------------------------------------------------
// Decoder GRU step: 6 waves (gate x K-half), each wave covers TWO m16 tiles
// (halves weight re-reads: ~500 -> ~250 MB/step). Grid (64, 8).
// ---------------------------------------------------------------------------
__global__ __launch_bounds__(384) void dec_gru3(
    const short8* __restrict__ hinH8, const short8* __restrict__ hinL8,
    const short8* __restrict__ gxH8, const short8* __restrict__ gxL8,
    const short8* __restrict__ WrH, const short8* __restrict__ WrL,
    const short8* __restrict__ WzH, const short8* __restrict__ WzL,
    const short8* __restrict__ WnhH, const short8* __restrict__ WnhL,
    const short8* __restrict__ WniH, const short8* __restrict__ WniL,
    const float* __restrict__ bih, const float* __restrict__ bhh,
    const float* __restrict__ hinF, float* __restrict__ houtF,
    short* __restrict__ hoH, short* __restrict__ hoL) {
    __shared__ float sC[8][2][16][16];
    __shared__ float sHo[2][16][16];
    int tid = threadIdx.x, lane = tid & 63, wave = tid >> 6;  // 0..5
    int g = blockIdx.x;
    int m16a = blockIdx.y * 2;
    int gate = wave >> 1, half = wave & 1;
    const short8* a0h = hinH8 + (size_t)m16a * 32 * 64 + (size_t)half * 16 * 64 + lane;
    const short8* a0l = hinL8 + (size_t)m16a * 32 * 64 + (size_t)half * 16 * 64 + lane;
    const short8* a1h = a0h + (size_t)32 * 64;
    const short8* a1l = a0l + (size_t)32 * 64;
    const short8* g0h = gxH8 + (size_t)m16a * 48 * 64 + (size_t)half * 24 * 64 + lane;
    const short8* g0l = gxL8 + (size_t)m16a * 48 * 64 + (size_t)half * 24 * 64 + lane;
    const short8* g1h = g0h + (size_t)48 * 64;
    const short8* g1l = g0l + (size_t)48 * 64;
    const short8 *whA, *wlA, *whB, *wlB;
    if (gate == 0) {
        whA = WrH + (size_t)g * 80 * 64 + (size_t)half * 16 * 64 + lane;
        wlA = WrL + (size_t)g * 80 * 64 + (size_t)half * 16 * 64 + lane;
        whB = WrH + (size_t)g * 80 * 64 + (size_t)(32 + half * 24) * 64 + lane;
        wlB = WrL + (size_t)g * 80 * 64 + (size_t)(32 + half * 24) * 64 + lane;
    } else if (gate == 1) {
        whA = WzH + (size_t)g * 80 * 64 + (size_t)half * 16 * 64 + lane;
        wlA = WzL + (size_t)g * 80 * 64 + (size_t)half * 16 * 64 + lane;
        whB = WzH + (size_t)g * 80 * 64 + (size_t)(32 + half * 24) * 64 + lane;
        wlB = WzL + (size_t)g * 80 * 64 + (size_t)(32 + half * 24) * 64 + lane;
    } else {
        whA = WnhH + (size_t)g * 32 * 64 + (size_t)half * 16 * 64 + lane;
        wlA = WnhL + (size_t)g * 32 * 64 + (size_t)half * 16 * 64 + lane;
        whB = WniH + (size_t)g * 48 * 64 + (size_t)half * 24 * 64 + lane;
        wlB = WniL + (size_t)g * 48 * 64 + (size_t)half * 24 * 64 + lane;
    }
    f32x4 accA0 = {0,0,0,0}, accA1 = {0,0,0,0};
    f32x4 accB0 = {0,0,0,0}, accB1 = {0,0,0,0};
    for (int kt = 0; kt < 16; kt++) {
        size_t o = (size_t)kt * 64;
        short8 WH = whA[o], WL = wlA[o];
        short8 A0H = a0h[o], A0L = a0l[o];
        MFMA(accA0, A0H, WH); MFMA(accA0, A0H, WL); MFMA(accA0, A0L, WH);
        short8 A1H = a1h[o], A1L = a1l[o];
        MFMA(accA1, A1H, WH); MFMA(accA1, A1H, WL); MFMA(accA1, A1L, WH);
    }
    for (int kt = 0; kt < 24; kt++) {
        size_t o = (size_t)kt * 64;
        short8 WH = whB[o], WL = wlB[o];
        short8 G0H = g0h[o], G0L = g0l[o];
        MFMA(accB0, G0H, WH); MFMA(accB0, G0H, WL); MFMA(accB0, G0L, WH);
        short8 G1H = g1h[o], G1L = g1l[o];
        MFMA(accB1, G1H, WH); MFMA(accB1, G1H, WL); MFMA(accB1, G1L, WH);
    }
    {
        int rsub = (lane >> 4) << 2, cn = lane & 15;
        if (wave < 4) {
#pragma unroll
            for (int j = 0; j < 4; j++) {
                sC[wave][0][rsub + j][cn] = accA0[j] + accB0[j];
                sC[wave][1][rsub + j][cn] = accA1[j] + accB1[j];
            }
        } else {
#pragma unroll
            for (int j = 0; j < 4; j++) {
                sC[wave][0][rsub + j][cn] = accA0[j];      // nh -> slots 4,5
                sC[wave][1][rsub + j][cn] = accA1[j];
                sC[wave + 2][0][rsub + j][cn] = accB0[j];  // ni -> slots 6,7
                sC[wave + 2][1][rsub + j][cn] = accB1[j];
            }
        }
    }
    __syncthreads();
    if (wave < 2) {
        int m16 = m16a + wave;
        int cu = g * 16 + (lane & 15);
        int rsub = (lane >> 4) << 2;
        float b_r = bih[cu] + bhh[cu];
        float b_z = bih[UDIM + cu] + bhh[UDIM + cu];
        float b_nh = bhh[2 * UDIM + cu];
        float b_ni = bih[2 * UDIM + cu];
#pragma unroll
        for (int j = 0; j < 4; j++) {
            int rr = rsub + j, cc = lane & 15;
            int b = m16 * 16 + rr;
            float rg = sigm(sC[0][wave][rr][cc] + sC[1][wave][rr][cc] + b_r);
            float zg = sigm(sC[2][wave][rr][cc] + sC[3][wave][rr][cc] + b_z);
            float nn = tanhf(sC[6][wave][rr][cc] + sC[7][wave][rr][cc] + b_ni +
                             rg * (sC[4][wave][rr][cc] + sC[5][wave][rr][cc] + b_nh));
            float hp = hinF[(size_t)b * UDIM + cu];
            float hv = (1.f - zg) * nn + zg * hp;
            houtF[(size_t)b * UDIM + cu] = hv;
            sHo[wave][rr][cc] = hv;
        }
    }
    __syncthreads();
    if (wave >= 2 && wave < 4 && lane < 32) {
        int tile = wave - 2;
        int m16 = m16a + tile;
        int rr = lane >> 1, oct = lane & 1;
        int brow = m16 * 16 + rr;
        int u0 = g * 16 + oct * 8;
        float v[8];
#pragma unroll
        for (int j = 0; j < 8; j++) v[j] = sHo[tile][rr][oct * 8 + j];
        writeSplit8(hoH, hoL, pkChunk(brow, u0, UDIM), v);
    }
}

// ---------------------------------------------------------------------------
// Attention + ctx + emb -> gx split-pack. 1024-thread blocks (16 waves/CU):
// score pass 16-wave s-stride; ctx pass 8-way s-split with LDS combine;
// emb reads pre-transposed bias-folded o2hT row (coalesced).
// ---------------------------------------------------------------------------
__global__ __launch_bounds__(1024) void attn_ctx(
    const float* __restrict__ encProj,
    const short* __restrict__ eaHi, const short* __restrict__ eaLo,
    const float* __restrict__ tmp2, const float* __restrict__ V_W,
    const float* __restrict__ V_b,
    const float* __restrict__ o2hT,
    const int* __restrict__ idx, short* __restrict__ gxHi, short* __restrict__ gxLo) {
    int b = blockIdx.x;
    int tid = threadIdx.x, lane = tid & 63, wave = tid >> 6;
    __shared__ float s_t2[UDIM];
    __shared__ float s_v[UDIM];
    __shared__ float s_attn[SLEN];
    __shared__ float s_part[7][128][9];  // pad 9 floats: conflict-free combine
    for (int u = tid; u < UDIM; u += 1024) {
        s_t2[u] = tmp2[(size_t)b * UDIM + u];
        s_v[u] = V_W[u];
    }
    __syncthreads();
    for (int s = wave; s < SLEN; s += 16) {
        const float4* ep4 = (const float4*)(encProj + ((size_t)b * SLEN + s) * UDIM);
        float p = 0.f;
        for (int u4 = lane; u4 < UDIM / 4; u4 += 64) {
            float4 e = ep4[u4];
            int u = 4 * u4;
            p += tanhf_fast(e.x + s_t2[u]) * s_v[u] +
                 tanhf_fast(e.y + s_t2[u + 1]) * s_v[u + 1] +
                 tanhf_fast(e.z + s_t2[u + 2]) * s_v[u + 2] +
                 tanhf_fast(e.w + s_t2[u + 3]) * s_v[u + 3];
        }
#pragma unroll
        for (int off = 32; off > 0; off >>= 1) p += __shfl_xor(p, off);
        if (lane == 0) s_attn[s] = p + V_b[0];
    }
    __syncthreads();
    if (tid < 64) {
        float v = s_attn[tid];
        float mx = v;
#pragma unroll
        for (int off = 32; off > 0; off >>= 1) mx = fmaxf(mx, __shfl_xor(mx, off));
        float e = expf(v - mx);
        float sum = e;
#pragma unroll
        for (int off = 32; off > 0; off >>= 1) sum += __shfl_xor(sum, off);
        s_attn[tid] = e / sum;
    }
    __syncthreads();
    {
        int grp = tid >> 7, tu = tid & 127;  // 8 s-groups x 128 u-threads
        int u0 = tu * 8;
        float a[8] = {0, 0, 0, 0, 0, 0, 0, 0};
        const short8* hi8 = (const short8*)eaHi;
        const short8* lo8 = (const short8*)eaLo;
        int lanePart = 16 * ((u0 >> 3) & 3);
        int colPart = u0 >> 5;
        for (int s = grp * 8; s < grp * 8 + 8; s++) {
            int r = b * SLEN + s;
            size_t ch = ((size_t)(r >> 4) * (UDIM >> 5) + colPart) * 64 + (r & 15) + lanePart;
            S8 h, l;
            h.v = hi8[ch];
            l.v = lo8[ch];
            float w = s_attn[s];
#pragma unroll
            for (int j = 0; j < 8; j++) a[j] += w * (bf2f(h.s[j]) + bf2f(l.s[j]));
        }
        if (grp) {
#pragma unroll
            for (int j = 0; j < 8; j++) s_part[grp - 1][tu][j] = a[j];
        }
        __syncthreads();
        if (tid < 128) {
#pragma unroll
            for (int gg = 0; gg < 7; gg++)
#pragma unroll
                for (int j = 0; j < 8; j++) a[j] += s_part[gg][tu][j];
            writeSplit8(gxHi, gxLo, pkChunk(b, u0, GXW), a);
        } else if (tid < 192) {
            int e0 = (tid - 128) * 8;
            int ib = idx[b];
            const float* row = o2hT + (size_t)ib * EDIM + e0;
            float v[8];
#pragma unroll
            for (int j = 0; j < 8; j++) v[j] = row[j];
            writeSplit8(gxHi, gxLo, pkChunk(b, UDIM + e0, GXW), v);
        }
    }
}

// ---------------------------------------------------------------------------
// Merged: pred=h@fc^T+b + parallel first-max argmax (blocks 0..15) AND
// tmp2=h@W2^T+b for the next step (blocks 16..143).
// ---------------------------------------------------------------------------
__global__ __launch_bounds__(256) void fcw2(
    const short8* __restrict__ hHi, const short8* __restrict__ hLo,
    const short8* __restrict__ fcH, const short8* __restrict__ fcL,
    const float* __restrict__ fc_b, float* __restrict__ pred,
    int* __restrict__ idx,
    const short8* __restrict__ w2H, const short8* __restrict__ w2L,
    const float* __restrict__ W2_b, float* __restrict__ tmp2) {
    __shared__ float sP[16][129];
    int tid = threadIdx.x, lane = tid & 63, wave = tid >> 6;
    if (blockIdx.x < 16) {
        int fm = blockIdx.x;
        const short8* ah = hHi + (size_t)fm * 32 * 64 + lane;
        const short8* al = hLo + (size_t)fm * 32 * 64 + lane;
        int n0 = 2 * wave, n1 = 2 * wave + 1;
        const short8* w0h = fcH + (size_t)n0 * 32 * 64 + lane;
        const short8* w0l = fcL + (size_t)n0 * 32 * 64 + lane;
        const short8* w1h = fcH + (size_t)n1 * 32 * 64 + lane;
        const short8* w1l = fcL + (size_t)n1 * 32 * 64 + lane;
        f32x4 a0 = {0,0,0,0}, a1 = {0,0,0,0};
        for (int kt = 0; kt < 32; kt++) {
            size_t o = (size_t)kt * 64;
            short8 AH = ah[o], AL = al[o];
            short8 W0H = w0h[o], W0L = w0l[o], W1H = w1h[o], W1L = w1l[o];
            MFMA(a0, AH, W0H); MFMA(a1, AH, W1H);
            MFMA(a0, AH, W0L); MFMA(a1, AH, W1L);
            MFMA(a0, AL, W0H); MFMA(a1, AL, W1H);
        }
        int cn = lane & 15, rsub = (lane >> 4) << 2;
#pragma unroll
        for (int j = 0; j < 4; j++) {
            sP[rsub + j][n0 * 16 + cn] = a0[j] + fc_b[n0 * 16 + cn];
            sP[rsub + j][n1 * 16 + cn] = a1[j] + fc_b[n1 * 16 + cn];
        }
        __syncthreads();
        {
            int row = tid >> 4, c0 = (tid & 15) * 8;
            float* pr = pred + (size_t)(fm * 16 + row) * VOUTD;
#pragma unroll
            for (int j = 0; j < 8; j++) pr[c0 + j] = sP[row][c0 + j];
        }
        if (tid < 128) {
            // 8 lanes per row, first-max semantics (strict > in scan order,
            // smaller index wins ties across segments)
            int row = tid >> 3, seg = tid & 7;
            float v = -1e30f;
            int bi = 0;
            int c0 = seg * 16;
            for (int j = c0; j < c0 + 16; j++) {
                float w = sP[row][j];
                if (w > v) { v = w; bi = j; }
            }
#pragma unroll
            for (int off = 1; off < 8; off <<= 1) {
                float ov = __shfl_xor(v, off);
                int obi = __shfl_xor(bi, off);
                if (ov > v || (ov == v && obi < bi)) { v = ov; bi = obi; }
            }
            if (seg == 0) idx[fm * 16 + row] = bi;
        }
    } else {
        int lin = blockIdx.x - 16;       // 0..127
        int bx = lin & 7, by = lin >> 3; // bm32 grid (8, 16)
        int m16 = bx * 2 + (wave & 1);
        int n16 = by * 4 + (wave >> 1) * 2;
        const short8* ah = hHi + (size_t)m16 * 32 * 64 + lane;
        const short8* al = hLo + (size_t)m16 * 32 * 64 + lane;
        const short8* w0h = w2H + (size_t)n16 * 32 * 64 + lane;
        const short8* w1h = w0h + (size_t)32 * 64;
        const short8* w0l = w2L + (size_t)n16 * 32 * 64 + lane;
        const short8* w1l = w0l + (size_t)32 * 64;
        f32x4 a0 = {0,0,0,0}, a1 = {0,0,0,0};
        for (int kt = 0; kt < 32; kt++) {
            size_t o = (size_t)kt * 64;
            short8 AH = ah[o], AL = al[o];
            short8 W0H = w0h[o], W0L = w0l[o], W1H = w1h[o], W1L = w1l[o];
            MFMA(a0, AH, W0H); MFMA(a1, AH, W1H);
            MFMA(a0, AH, W0L); MFMA(a1, AH, W1L);
            MFMA(a0, AL, W0H); MFMA(a1, AL, W1H);
        }
        int rsub = (lane >> 4) * 4, cn = lane & 15;
        float b0 = W2_b[(n16 + 0) * 16 + cn];
        float b1 = W2_b[(n16 + 1) * 16 + cn];
#pragma unroll
        for (int r = 0; r < 4; r++) {
            int row = m16 * 16 + rsub + r;
            tmp2[(size_t)row * UDIM + (n16 + 0) * 16 + cn] = a0[r] + b0;
            tmp2[(size_t)row * UDIM + (n16 + 1) * 16 + cn] = a1[r] + b1;
        }
    }
}

// ---------------------------------------------------------------------------
extern "C" void kernel_launch(void* const* d_in, const int* in_sizes, int n_in,
                              void* d_out, int out_size, void* d_ws, size_t ws_size,
                              hipStream_t stream) {
    const float* x       = (const float*)d_in[0];
    const int*   x_len   = (const int*)d_in[1];
    const float* enc_Wih = (const float*)d_in[2];
    const float* enc_Whh = (const float*)d_in[3];
    const float* enc_bih = (const float*)d_in[4];
    const float* enc_bhh = (const float*)d_in[5];
    const float* dec_Wih = (const float*)d_in[6];
    const float* dec_Whh = (const float*)d_in[7];
    const float* dec_bih = (const float*)d_in[8];
    const float* dec_bhh = (const float*)d_in[9];
    const float* o2h_W   = (const float*)d_in[10];
    const float* o2h_b   = (const float*)d_in[11];
    const float* fc_W    = (const float*)d_in[12];
    const float* fc_b    = (const float*)d_in[13];
    const float* W1_W    = (const float*)d_in[14];
    const float* W1_b    = (const float*)d_in[15];
    const float* W2_W    = (const float*)d_in[16];
    const float* W2_b    = (const float*)d_in[17];
    const float* V_W     = (const float*)d_in[18];
    const float* V_b     = (const float*)d_in[19];
    float* out = (float*)d_out;

    char* p = (char*)d_ws;
    auto alloc = [&](size_t bytes) -> char* {
        char* q = p;
        p += (bytes + 255) & ~(size_t)255;
        return q;
    };
    float* hAF  = (float*)alloc((size_t)BATCH * UDIM * 4);
    float* hBF  = (float*)alloc((size_t)BATCH * UDIM * 4);
    short* hAH  = (short*)alloc((size_t)BATCH * UDIM * 2);
    short* hAL  = (short*)alloc((size_t)BATCH * UDIM * 2);
    short* hBH  = (short*)alloc((size_t)BATCH * UDIM * 2);
    short* hBL  = (short*)alloc((size_t)BATCH * UDIM * 2);
    float* tmp2 = (float*)alloc((size_t)BATCH * UDIM * 4);
    short* gxHi = (short*)alloc((size_t)BATCH * GXW * 2);
    short* gxLo = (short*)alloc((size_t)BATCH * GXW * 2);
    short* encAHi = (short*)alloc((size_t)BATCH * SLEN * UDIM * 2);
    short* encALo = (short*)alloc((size_t)BATCH * SLEN * UDIM * 2);
    float* encProjF = (float*)alloc((size_t)BATCH * SLEN * UDIM * 4);
    float* gihBuf = (float*)alloc((size_t)8 * BATCH * U3 * 4);
    short* eWihH = (short*)alloc((size_t)U3 * VIND * 2);
    short* eWihL = (short*)alloc((size_t)U3 * VIND * 2);
    short* eWrH = (short*)alloc((size_t)UDIM * UDIM * 2);
    short* eWrL = (short*)alloc((size_t)UDIM * UDIM * 2);
    short* eWzH = (short*)alloc((size_t)UDIM * UDIM * 2);
    short* eWzL = (short*)alloc((size_t)UDIM * UDIM * 2);
    short* eWnH = (short*)alloc((size_t)UDIM * UDIM * 2);
    short* eWnL = (short*)alloc((size_t)UDIM * UDIM * 2);
    short* dWrH = (short*)alloc((size_t)UDIM * 2560 * 2);
    short* dWrL = (short*)alloc((size_t)UDIM * 2560 * 2);
    short* dWzH = (short*)alloc((size_t)UDIM * 2560 * 2);
    short* dWzL = (short*)alloc((size_t)UDIM * 2560 * 2);
    short* dWnhH = (short*)alloc((size_t)UDIM * UDIM * 2);
    short* dWnhL = (short*)alloc((size_t)UDIM * UDIM * 2);
    short* dWniH = (short*)alloc((size_t)UDIM * GXW * 2);
    short* dWniL = (short*)alloc((size_t)UDIM * GXW * 2);
    short* w1Hi = (short*)alloc((size_t)UDIM * UDIM * 2);
    short* w1Lo = (short*)alloc((size_t)UDIM * UDIM * 2);
    short* w2Hi = (short*)alloc((size_t)UDIM * UDIM * 2);
    short* w2Lo = (short*)alloc((size_t)UDIM * UDIM * 2);
    short* fcHi = (short*)alloc((size_t)VOUTD * UDIM * 2);
    short* fcLo = (short*)alloc((size_t)VOUTD * UDIM * 2);
    short* xHi  = (short*)alloc((size_t)SLEN * BATCH * VIND * 2);
    short* xLo  = (short*)alloc((size_t)SLEN * BATCH * VIND * 2);
    int*   idx  = (int*)alloc(BATCH * 4);
    float* o2hT = (float*)alloc((size_t)VOUTD * EDIM * 4);

    init_kernel<<<(BATCH * UDIM + 255) / 256, 256, 0, stream>>>(
        hAF, hAH, hAL, out, idx, o2h_W, o2h_b, o2hT);

    // ---- single packing kernel for all weights + x ----
    {
        PackArgs pa;
        int cs = 0, n = 0;
        auto seg = [&](const float* sA, int KA, int offA, const float* sB, int KB,
                       int offB, short* Hi, short* Lo, int R) {
            pa.s[n] = {sA, sB, Hi, Lo, KA, KB, offA, offB, cs};
            cs += R * (KA + KB) / 8;
            n++;
        };
        seg(enc_Wih, VIND, 0, nullptr, 0, 0, eWihH, eWihL, U3);
        seg(enc_Whh, UDIM, 0, nullptr, 0, 0, eWrH, eWrL, UDIM);
        seg(enc_Whh, UDIM, UDIM, nullptr, 0, 0, eWzH, eWzL, UDIM);
        seg(enc_Whh, UDIM, 2 * UDIM, nullptr, 0, 0, eWnH, eWnL, UDIM);
        seg(dec_Whh, UDIM, 0, dec_Wih, GXW, 0, dWrH, dWrL, UDIM);
        seg(dec_Whh, UDIM, UDIM, dec_Wih, GXW, UDIM, dWzH, dWzL, UDIM);
        seg(dec_Whh, UDIM, 2 * UDIM, nullptr, 0, 0, dWnhH, dWnhL, UDIM);
        seg(dec_Wih, GXW, 2 * UDIM, nullptr, 0, 0, dWniH, dWniL, UDIM);
        seg(W1_W, UDIM, 0, nullptr, 0, 0, w1Hi, w1Lo, UDIM);
        seg(W2_W, UDIM, 0, nullptr, 0, 0, w2Hi, w2Lo, UDIM);
        seg(fc_W, UDIM, 0, nullptr, 0, 0, fcHi, fcLo, VOUTD);
        seg(x, VIND, 0, nullptr, 0, 0, xHi, xLo, SLEN * BATCH);
        pack_all<<<(cs + 255) / 256, 256, 0, stream>>>(pa, cs);
    }

    // ---- encoder: 8 chunks of (gi chunk-GEMM + 8 fused GRU steps) ----
    float* hcF = hAF; float* hnF = hBF;
    short *hcH = hAH, *hcL = hAL, *hnH = hBH, *hnL = hBL;
    for (int c = 0; c < 8; c++) {
        gemm_w<<<dim3(32, 24), 256, 0, stream>>>(
            (const short8*)xHi + (size_t)c * 128 * 4 * 64,
            (const short8*)xLo + (size_t)c * 128 * 4 * 64,
            (const short8*)eWihH, (const short8*)eWihL,
            nullptr, gihBuf, VIND / 32, U3);
        for (int tt = 0; tt < 8; tt++) {
            int t = c * 8 + tt;
            enc_gru3<<<dim3(64, 8), 384, 0, stream>>>(
                (const short8*)hcH, (const short8*)hcL,
                (const short8*)eWrH, (const short8*)eWrL,
                (const short8*)eWzH, (const short8*)eWzL,
                (const short8*)eWnH, (const short8*)eWnL,
                gihBuf, enc_bih, enc_bhh, hcF, hnF, hnH, hnL,
                encAHi, encALo, x_len, t);
            { float* tf = hcF; hcF = hnF; hnF = tf; }
            { short* th = hcH; hcH = hnH; hnH = th; th = hcL; hcL = hnL; hnL = th; }
        }
    }

    // ---- enc_proj = enc_out @ W1^T + W1_b (fp32, BN=128 blocks) ----
    gemm_w<<<dim3(SLEN * BATCH / 64, UDIM / 128), 256, 0, stream>>>(
        (const short8*)encAHi, (const short8*)encALo,
        (const short8*)w1Hi, (const short8*)w1Lo,
        W1_b, encProjF, UDIM / 32, UDIM);

    // ---- initial tmp2 from encoder hidden ----
    gemm_bm32<<<dim3(BATCH / 32, UDIM / 64), 256, 0, stream>>>(
        (const short8*)hcH, (const short8*)hcL,
        (const short8*)w2Hi, (const short8*)w2Lo,
        W2_b, tmp2, UDIM / 32, UDIM);

    // ---- greedy decode: 24 steps x 3 dispatches ----
    for (int st = 0; st < TDEC - 1; st++) {
        attn_ctx<<<BATCH, 1024, 0, stream>>>(
            encProjF, encAHi, encALo, tmp2, V_W, V_b, o2hT, idx, gxHi, gxLo);
        dec_gru3<<<dim3(64, 8), 384, 0, stream>>>(
            (const short8*)hcH, (const short8*)hcL,
            (const short8*)gxHi, (const short8*)gxLo,
            (const short8*)dWrH, (const short8*)dWrL,
            (const short8*)dWzH, (const short8*)dWzL,
            (const short8*)dWnhH, (const short8*)dWnhL,
            (const short8*)dWniH, (const short8*)dWniL,
            dec_bih, dec_bhh, hcF, hnF, hnH, hnL);
        float* pred = out + (size_t)(1 + st) * BATCH * VOUTD;
        fcw2<<<144, 256, 0, stream>>>(
            (const short8*)hnH, (const short8*)hnL,
            (const short8*)fcHi, (const short8*)fcLo,
            fc_b, pred, idx,
            (const short8*)w2Hi, (const short8*)w2Lo, W2_b, tmp2);
        { float* tf = hcF; hcF = hnF; hnF = tf; }
        { short* th = hcH; hcH = hnH; hnH = th; th = hcL; hcL = hnL; hnL = th; }
    }
}

// Round 6
// 3464.223 us; speedup vs baseline: 3.7311x; 1.0067x over previous
//
#include <hip/hip_runtime.h>
#include <math.h>

#define SLEN 64
#define BATCH 256
#define VIND 128
#define VOUTD 128
#define UDIM 1024
#define EDIM 512
#define TDEC 25
#define GXW 1536
#define U3 3072
#define NSEG 12

typedef __attribute__((ext_vector_type(8))) short short8;
typedef __attribute__((ext_vector_type(4))) float f32x4;

#define MFMA(acc, A, B) acc = __builtin_amdgcn_mfma_f32_16x16x32_bf16((A), (B), (acc), 0, 0, 0)

// libm sigmoid/tanh in the RECURRENT path (gates): fast variants drift over the
// 64-step encoder + 24-step decoder recurrence and flip greedy argmax (R1 fail).
__device__ __forceinline__ float sigm(float x) { return 1.f / (1.f + expf(-x)); }

// fast tanh for the attention SCORE path only (non-recurrent-critical)
__device__ __forceinline__ float tanhf_fast(float x) {
    float ax = fabsf(x);
    float e = __expf(-2.f * ax);
    float t = (1.f - e) / (1.f + e);
    return copysignf(t, x);
}

__device__ __forceinline__ short f2bf(float f) {
    unsigned u = __float_as_uint(f);
    u += 0x7FFF + ((u >> 16) & 1);
    return (short)(u >> 16);
}
__device__ __forceinline__ float bf2f(short h) {
    return __uint_as_float(((unsigned)(unsigned short)h) << 16);
}

// fragment-major packed layout for operand X[R][K]:
// chunk(r,k) holds X[r][k..k+8); lane = (r&15) + 16*((k>>3)&3)
__device__ __forceinline__ size_t pkChunk(int r, int k, int K) {
    return ((size_t)(r >> 4) * (K >> 5) + (k >> 5)) * 64 + ((r & 15) + 16 * ((k >> 3) & 3));
}

union S8 { short s[8]; short8 v; };

__device__ __forceinline__ void writeSplit8(short* Hi, short* Lo, size_t chunk,
                                            const float* vals) {
    S8 h, l;
#pragma unroll
    for (int j = 0; j < 8; j++) {
        short hb = f2bf(vals[j]);
        h.s[j] = hb;
        l.s[j] = f2bf(vals[j] - bf2f(hb));
    }
    ((short8*)Hi)[chunk] = h.v;
    ((short8*)Lo)[chunk] = l.v;
}

// ---------------------------------------------------------------------------
__global__ void init_kernel(float* __restrict__ h0, short* __restrict__ hpHi,
                            short* __restrict__ hpLo, float* __restrict__ out0,
                            int* __restrict__ idx,
                            const float* __restrict__ o2h_W,
                            const float* __restrict__ o2h_b,
                            float* __restrict__ o2hT) {
    int i = blockIdx.x * 256 + threadIdx.x;
    if (i < BATCH * UDIM) { h0[i] = 0.f; hpHi[i] = 0; hpLo[i] = 0; }
    if (i < BATCH * VOUTD) out0[i] = ((i & (VOUTD - 1)) == 0) ? 1.f : 0.f;
    if (i < BATCH) idx[i] = 0;
    if (i < VOUTD * EDIM) {
        // o2hT[v][e] = o2h_W[e][v] + o2h_b[e]  (bias folded, row-read at decode)
        int v = i >> 9, e = i & (EDIM - 1);
        o2hT[i] = o2h_W[(size_t)e * VOUTD + v] + o2h_b[e];
    }
}

// ---------------------------------------------------------------------------
// All weight/input packing in ONE kernel: segment table passed by value.
// ---------------------------------------------------------------------------
struct PackSeg {
    const float* sA; const float* sB;
    short* Hi; short* Lo;
    int KA, KB, offA, offB, chunkStart;
};
struct PackArgs { PackSeg s[NSEG]; };

__global__ void pack_all(PackArgs pa, int total) {
    int gid = blockIdx.x * 256 + threadIdx.x;
    if (gid >= total) return;
    int si = 0;
#pragma unroll
    for (int i = 1; i < NSEG; i++) si = (gid >= pa.s[i].chunkStart) ? i : si;
    PackSeg sg = pa.s[si];
    int local = gid - sg.chunkStart;
    int K = sg.KA + sg.KB;
    int cpr = K >> 3;
    int r = local / cpr, k0 = (local - r * cpr) * 8;
    const float* src = (k0 < sg.KA)
        ? sg.sA + (size_t)(sg.offA + r) * sg.KA + k0
        : sg.sB + (size_t)(sg.offB + r) * sg.KB + (k0 - sg.KA);
    float v[8];
#pragma unroll
    for (int j = 0; j < 8; j++) v[j] = src[j];
    writeSplit8(sg.Hi, sg.Lo, pkChunk(r, k0, K), v);
}

// ---------------------------------------------------------------------------
// Split-bf16 3-pass MFMA GEMM, BM=64 x BN=128 block (4 waves of 32x64).
// ---------------------------------------------------------------------------
__global__ __launch_bounds__(256) void gemm_w(
    const short8* __restrict__ Ahi, const short8* __restrict__ Alo,
    const short8* __restrict__ Whi, const short8* __restrict__ Wlo,
    const float* __restrict__ bias, float* __restrict__ C,
    int KT, int N) {
    int tid = threadIdx.x, lane = tid & 63, wave = tid >> 6;
    int m16 = blockIdx.x * 4 + (wave & 1) * 2;
    int nb = blockIdx.y * 8 + (wave >> 1) * 4;
    const short8* a0h = Ahi + (size_t)m16 * KT * 64 + lane;
    const short8* a1h = a0h + (size_t)KT * 64;
    const short8* a0l = Alo + (size_t)m16 * KT * 64 + lane;
    const short8* a1l = a0l + (size_t)KT * 64;
    const short8* w0h = Whi + (size_t)(nb + 0) * KT * 64 + lane;
    const short8* w1h = Whi + (size_t)(nb + 1) * KT * 64 + lane;
    const short8* w2h = Whi + (size_t)(nb + 2) * KT * 64 + lane;
    const short8* w3h = Whi + (size_t)(nb + 3) * KT * 64 + lane;
    const short8* w0l = Wlo + (size_t)(nb + 0) * KT * 64 + lane;
    const short8* w1l = Wlo + (size_t)(nb + 1) * KT * 64 + lane;
    const short8* w2l = Wlo + (size_t)(nb + 2) * KT * 64 + lane;
    const short8* w3l = Wlo + (size_t)(nb + 3) * KT * 64 + lane;
    f32x4 acc0[4] = {}, acc1[4] = {};

    for (int kt = 0; kt < KT; kt++) {
        size_t o = (size_t)kt * 64;
        short8 A0H = a0h[o], A1H = a1h[o], A0L = a0l[o], A1L = a1l[o];
        short8 WH0 = w0h[o], WL0 = w0l[o];
        MFMA(acc0[0], A0H, WH0); MFMA(acc1[0], A1H, WH0);
        MFMA(acc0[0], A0H, WL0); MFMA(acc1[0], A1H, WL0);
        MFMA(acc0[0], A0L, WH0); MFMA(acc1[0], A1L, WH0);
        short8 WH1 = w1h[o], WL1 = w1l[o];
        MFMA(acc0[1], A0H, WH1); MFMA(acc1[1], A1H, WH1);
        MFMA(acc0[1], A0H, WL1); MFMA(acc1[1], A1H, WL1);
        MFMA(acc0[1], A0L, WH1); MFMA(acc1[1], A1L, WH1);
        short8 WH2 = w2h[o], WL2 = w2l[o];
        MFMA(acc0[2], A0H, WH2); MFMA(acc1[2], A1H, WH2);
        MFMA(acc0[2], A0H, WL2); MFMA(acc1[2], A1H, WL2);
        MFMA(acc0[2], A0L, WH2); MFMA(acc1[2], A1L, WH2);
        short8 WH3 = w3h[o], WL3 = w3l[o];
        MFMA(acc0[3], A0H, WH3); MFMA(acc1[3], A1H, WH3);
        MFMA(acc0[3], A0H, WL3); MFMA(acc1[3], A1H, WL3);
        MFMA(acc0[3], A0L, WH3); MFMA(acc1[3], A1L, WH3);
    }
    int rsub = (lane >> 4) * 4, cn = lane & 15;
    int row0 = (m16 + 0) * 16 + rsub;
    int row1 = (m16 + 1) * 16 + rsub;
#pragma unroll
    for (int j = 0; j < 4; j++) {
        int col = (nb + j) * 16 + cn;
        float bb = bias ? bias[col] : 0.f;
#pragma unroll
        for (int r = 0; r < 4; r++) {
            C[(size_t)(row0 + r) * N + col] = acc0[j][r] + bb;
            C[(size_t)(row1 + r) * N + col] = acc1[j][r] + bb;
        }
    }
}

// ---------------------------------------------------------------------------
// BM=32 GEMM for the pre-loop tmp2. Grid (M/32, N/64).
// ---------------------------------------------------------------------------
__global__ __launch_bounds__(256) void gemm_bm32(
    const short8* __restrict__ Ahi, const short8* __restrict__ Alo,
    const short8* __restrict__ Whi, const short8* __restrict__ Wlo,
    const float* __restrict__ bias, float* __restrict__ C,
    int KT, int N) {
    int tid = threadIdx.x, lane = tid & 63, wave = tid >> 6;
    int m16 = blockIdx.x * 2 + (wave & 1);
    int n16 = blockIdx.y * 4 + (wave >> 1) * 2;
    const short8* ah = Ahi + (size_t)m16 * KT * 64 + lane;
    const short8* al = Alo + (size_t)m16 * KT * 64 + lane;
    const short8* w0h = Whi + (size_t)n16 * KT * 64 + lane;
    const short8* w1h = w0h + (size_t)KT * 64;
    const short8* w0l = Wlo + (size_t)n16 * KT * 64 + lane;
    const short8* w1l = w0l + (size_t)KT * 64;
    f32x4 a0 = {0,0,0,0}, a1 = {0,0,0,0};
    for (int kt = 0; kt < KT; kt++) {
        size_t o = (size_t)kt * 64;
        short8 AH = ah[o], AL = al[o];
        short8 W0H = w0h[o], W0L = w0l[o], W1H = w1h[o], W1L = w1l[o];
        MFMA(a0, AH, W0H); MFMA(a1, AH, W1H);
        MFMA(a0, AH, W0L); MFMA(a1, AH, W1L);
        MFMA(a0, AL, W0H); MFMA(a1, AL, W1H);
    }
    int rsub = (lane >> 4) * 4, cn = lane & 15;
    float b0 = bias ? bias[(n16 + 0) * 16 + cn] : 0.f;
    float b1 = bias ? bias[(n16 + 1) * 16 + cn] : 0.f;
#pragma unroll
    for (int r = 0; r < 4; r++) {
        int row = m16 * 16 + rsub + r;
        C[(size_t)row * N + (n16 + 0) * 16 + cn] = a0[r] + b0;
        C[(size_t)row * N + (n16 + 1) * 16 + cn] = a1[r] + b1;
    }
}

// ---------------------------------------------------------------------------
// Encoder GRU step: 12 waves = (gate x K-half x m-pair); block covers FOUR
// m16 tiles. Weight slice shared by the two m-pair waves -> L1/L2 hits;
// weight traffic 100 -> 50 MB/step at unchanged 12 waves/CU. Grid (64, 4).
// Math bitwise-identical to R5 (same K-halves, same kt order per tile).
// ---------------------------------------------------------------------------
__global__ __launch_bounds__(768) void enc_gru3(
    const short8* __restrict__ hinH8, const short8* __restrict__ hinL8,
    const short8* __restrict__ WrH, const short8* __restrict__ WrL,
    const short8* __restrict__ WzH, const short8* __restrict__ WzL,
    const short8* __restrict__ WnH, const short8* __restrict__ WnL,
    const float* __restrict__ gi,
    const float* __restrict__ bih, const float* __restrict__ bhh,
    const float* __restrict__ hinF, float* __restrict__ houtF,
    short* __restrict__ hoH, short* __restrict__ hoL,
    short* __restrict__ eaHi, short* __restrict__ eaLo,
    const int* __restrict__ x_len, int t) {
    __shared__ float sC[6][4][16][16];
    __shared__ float sHo[4][16][16];
    __shared__ float sEo[4][16][16];
    int tid = threadIdx.x, lane = tid & 63, wave = tid >> 6;  // wave 0..11
    int g = blockIdx.x;
    int m16a = blockIdx.y * 4;
    int gate = wave >> 2, hm = wave & 3, half = hm >> 1, mp = hm & 1;
    int t0 = mp * 2;  // this wave's tiles: t0, t0+1
    const short8* a0h = hinH8 + (size_t)(m16a + t0) * 32 * 64 + (size_t)half * 16 * 64 + lane;
    const short8* a0l = hinL8 + (size_t)(m16a + t0) * 32 * 64 + (size_t)half * 16 * 64 + lane;
    const short8* a1h = a0h + (size_t)32 * 64;
    const short8* a1l = a0l + (size_t)32 * 64;
    const short8* WH0 = (gate == 0) ? WrH : (gate == 1) ? WzH : WnH;
    const short8* WL0 = (gate == 0) ? WrL : (gate == 1) ? WzL : WnL;
    const short8* wh = WH0 + (size_t)g * 32 * 64 + (size_t)half * 16 * 64 + lane;
    const short8* wl = WL0 + (size_t)g * 32 * 64 + (size_t)half * 16 * 64 + lane;
    f32x4 acc0 = {0, 0, 0, 0}, acc1 = {0, 0, 0, 0};
    for (int kt = 0; kt < 16; kt++) {
        size_t o = (size_t)kt * 64;
        short8 WH = wh[o], WL = wl[o];
        short8 A0H = a0h[o], A0L = a0l[o];
        MFMA(acc0, A0H, WH); MFMA(acc0, A0H, WL); MFMA(acc0, A0L, WH);
        short8 A1H = a1h[o], A1L = a1l[o];
        MFMA(acc1, A1H, WH); MFMA(acc1, A1H, WL); MFMA(acc1, A1L, WH);
    }
    {
        int slot = gate * 2 + half;
        int rsub = (lane >> 4) << 2, cn = lane & 15;
#pragma unroll
        for (int j = 0; j < 4; j++) {
            sC[slot][t0 + 0][rsub + j][cn] = acc0[j];
            sC[slot][t0 + 1][rsub + j][cn] = acc1[j];
        }
    }
    __syncthreads();
    if (wave < 4) {
        int tile = wave;
        int m16 = m16a + tile;
        int cu = g * 16 + (lane & 15);
        int rsub = (lane >> 4) << 2;
        float b_r = bih[cu] + bhh[cu];
        float b_z = bih[UDIM + cu] + bhh[UDIM + cu];
        float b_nh = bhh[2 * UDIM + cu];
        float b_ni = bih[2 * UDIM + cu];
        int growLocal = (t & 7) * 256;
#pragma unroll
        for (int j = 0; j < 4; j++) {
            int rr = rsub + j, cc = lane & 15;
            int b = m16 * 16 + rr;
            const float* gr = gi + (size_t)(growLocal + b) * U3;
            float rg = sigm(sC[0][tile][rr][cc] + sC[1][tile][rr][cc] + gr[cu] + b_r);
            float zg = sigm(sC[2][tile][rr][cc] + sC[3][tile][rr][cc] + gr[UDIM + cu] + b_z);
            float nn = tanhf(gr[2 * UDIM + cu] + b_ni +
                             rg * (sC[4][tile][rr][cc] + sC[5][tile][rr][cc] + b_nh));
            float hp = hinF[(size_t)b * UDIM + cu];
            float hv = (1.f - zg) * nn + zg * hp;
            bool msk = t < x_len[b];
            float ho = msk ? hv : hp;
            houtF[(size_t)b * UDIM + cu] = ho;
            sHo[tile][rr][cc] = ho;
            sEo[tile][rr][cc] = msk ? hv : 0.f;
        }
    }
    __syncthreads();
    if (wave >= 4 && wave < 8 && lane < 32) {
        int tile = wave - 4;
        int m16 = m16a + tile;
        int rr = lane >> 1, oct = lane & 1;
        int brow = m16 * 16 + rr;
        int u0 = g * 16 + oct * 8;
        float v[8];
#pragma unroll
        for (int j = 0; j < 8; j++) v[j] = sHo[tile][rr][oct * 8 + j];
        writeSplit8(hoH, hoL, pkChunk(brow, u0, UDIM), v);
#pragma unroll
        for (int j = 0; j < 8; j++) v[j] = sEo[tile][rr][oct * 8 + j];
        writeSplit8(eaHi, eaLo, pkChunk(brow * SLEN + t, u0, UDIM), v);
    }
}

// ---------------------------------------------------------------------------
// Decoder GRU step: 12 waves = (gate x K-half x m-pair); block covers FOUR
// m16 tiles. Weight traffic 250 -> 125 MB/step at 12 waves/CU. Grid (64, 4).
// ---------------------------------------------------------------------------
__global__ __launch_bounds__(768) void dec_gru3(
    const short8* __restrict__ hinH8, const short8* __restrict__ hinL8,
    const short8* __restrict__ gxH8, const short8* __restrict__ gxL8,
    const short8* __restrict__ WrH, const short8* __restrict__ WrL,
    const short8* __restrict__ WzH, const short8* __restrict__ WzL,
    const short8* __restrict__ WnhH, const short8* __restrict__ WnhL,
    const short8* __restrict__ WniH, const short8* __restrict__ WniL,
    const float* __restrict__ bih, const float* __restrict__ bhh,
    const float* __restrict__ hinF, float* __restrict__ houtF,
    short* __restrict__ hoH, short* __restrict__ hoL) {
    __shared__ float sC[8][4][16][16];
    __shared__ float sHo[4][16][16];
    int tid = threadIdx.x, lane = tid & 63, wave = tid >> 6;  // 0..11
    int g = blockIdx.x;
    int m16a = blockIdx.y * 4;
    int gate = wave >> 2, hm = wave & 3, half = hm >> 1, mp = hm & 1;
    int t0 = mp * 2;
    const short8* a0h = hinH8 + (size_t)(m16a + t0) * 32 * 64 + (size_t)half * 16 * 64 + lane;
    const short8* a0l = hinL8 + (size_t)(m16a + t0) * 32 * 64 + (size_t)half * 16 * 64 + lane;
    const short8* a1h = a0h + (size_t)32 * 64;
    const short8* a1l = a0l + (size_t)32 * 64;
    const short8* g0h = gxH8 + (size_t)(m16a + t0) * 48 * 64 + (size_t)half * 24 * 64 + lane;
    const short8* g0l = gxL8 + (size_t)(m16a + t0) * 48 * 64 + (size_t)half * 24 * 64 + lane;
    const short8* g1h = g0h + (size_t)48 * 64;
    const short8* g1l = g0l + (size_t)48 * 64;
    const short8 *whA, *wlA, *whB, *wlB;
    if (gate == 0) {
        whA = WrH + (size_t)g * 80 * 64 + (size_t)half * 16 * 64 + lane;
        wlA = WrL + (size_t)g * 80 * 64 + (size_t)half * 16 * 64 + lane;
        whB = WrH + (size_t)g * 80 * 64 + (size_t)(32 + half * 24) * 64 + lane;
        wlB = WrL + (size_t)g * 80 * 64 + (size_t)(32 + half * 24) * 64 + lane;
    } else if (gate == 1) {
        whA = WzH + (size_t)g * 80 * 64 + (size_t)half * 16 * 64 + lane;
        wlA = WzL + (size_t)g * 80 * 64 + (size_t)half * 16 * 64 + lane;
        whB = WzH + (size_t)g * 80 * 64 + (size_t)(32 + half * 24) * 64 + lane;
        wlB = WzL + (size_t)g * 80 * 64 + (size_t)(32 + half * 24) * 64 + lane;
    } else {
        whA = WnhH + (size_t)g * 32 * 64 + (size_t)half * 16 * 64 + lane;
        wlA = WnhL + (size_t)g * 32 * 64 + (size_t)half * 16 * 64 + lane;
        whB = WniH + (size_t)g * 48 * 64 + (size_t)half * 24 * 64 + lane;
        wlB = WniL + (size_t)g * 48 * 64 + (size_t)half * 24 * 64 + lane;
    }
    f32x4 accA0 = {0,0,0,0}, accA1 = {0,0,0,0};
    f32x4 accB0 = {0,0,0,0}, accB1 = {0,0,0,0};
    for (int kt = 0; kt < 16; kt++) {
        size_t o = (size_t)kt * 64;
        short8 WH = whA[o], WL = wlA[o];
        short8 A0H = a0h[o], A0L = a0l[o];
        MFMA(accA0, A0H, WH); MFMA(accA0, A0H, WL); MFMA(accA0, A0L, WH);
        short8 A1H = a1h[o], A1L = a1l[o];
        MFMA(accA1, A1H, WH); MFMA(accA1, A1H, WL); MFMA(accA1, A1L, WH);
    }
    for (int kt = 0; kt < 24; kt++) {
        size_t o = (size_t)kt * 64;
        short8 WH = whB[o], WL = wlB[o];
        short8 G0H = g0h[o], G0L = g0l[o];
        MFMA(accB0, G0H, WH); MFMA(accB0, G0H, WL); MFMA(accB0, G0L, WH);
        short8 G1H = g1h[o], G1L = g1l[o];
        MFMA(accB1, G1H, WH); MFMA(accB1, G1H, WL); MFMA(accB1, G1L, WH);
    }
    {
        int rsub = (lane >> 4) << 2, cn = lane & 15;
        if (gate < 2) {
            int slot = gate * 2 + half;
#pragma unroll
            for (int j = 0; j < 4; j++) {
                sC[slot][t0 + 0][rsub + j][cn] = accA0[j] + accB0[j];
                sC[slot][t0 + 1][rsub + j][cn] = accA1[j] + accB1[j];
            }
        } else {
#pragma unroll
            for (int j = 0; j < 4; j++) {
                sC[4 + half][t0 + 0][rsub + j][cn] = accA0[j];  // nh
                sC[4 + half][t0 + 1][rsub + j][cn] = accA1[j];
                sC[6 + half][t0 + 0][rsub + j][cn] = accB0[j];  // ni
                sC[6 + half][t0 + 1][rsub + j][cn] = accB1[j];
            }
        }
    }
    __syncthreads();
    if (wave < 4) {
        int tile = wave;
        int m16 = m16a + tile;
        int cu = g * 16 + (lane & 15);
        int rsub = (lane >> 4) << 2;
        float b_r = bih[cu] + bhh[cu];
        float b_z = bih[UDIM + cu] + bhh[UDIM + cu];
        float b_nh = bhh[2 * UDIM + cu];
        float b_ni = bih[2 * UDIM + cu];
#pragma unroll
        for (int j = 0; j < 4; j++) {
            int rr = rsub + j, cc = lane & 15;
            int b = m16 * 16 + rr;
            float rg = sigm(sC[0][tile][rr][cc] + sC[1][tile][rr][cc] + b_r);
            float zg = sigm(sC[2][tile][rr][cc] + sC[3][tile][rr][cc] + b_z);
            float nn = tanhf(sC[6][tile][rr][cc] + sC[7][tile][rr][cc] + b_ni +
                             rg * (sC[4][tile][rr][cc] + sC[5][tile][rr][cc] + b_nh));
            float hp = hinF[(size_t)b * UDIM + cu];
            float hv = (1.f - zg) * nn + zg * hp;
            houtF[(size_t)b * UDIM + cu] = hv;
            sHo[tile][rr][cc] = hv;
        }
    }
    __syncthreads();
    if (wave >= 4 && wave < 8 && lane < 32) {
        int tile = wave - 4;
        int m16 = m16a + tile;
        int rr = lane >> 1, oct = lane & 1;
        int brow = m16 * 16 + rr;
        int u0 = g * 16 + oct * 8;
        float v[8];
#pragma unroll
        for (int j = 0; j < 8; j++) v[j] = sHo[tile][rr][oct * 8 + j];
        writeSplit8(hoH, hoL, pkChunk(brow, u0, UDIM), v);
    }
}

// ---------------------------------------------------------------------------
// Attention + ctx + emb -> gx split-pack. 1024-thread blocks (16 waves/CU):
// score pass 16-wave s-stride; ctx pass 8-way s-split with LDS combine;
// emb reads pre-transposed bias-folded o2hT row (coalesced).
// ---------------------------------------------------------------------------
__global__ __launch_bounds__(1024) void attn_ctx(
    const float* __restrict__ encProj,
    const short* __restrict__ eaHi, const short* __restrict__ eaLo,
    const float* __restrict__ tmp2, const float* __restrict__ V_W,
    const float* __restrict__ V_b,
    const float* __restrict__ o2hT,
    const int* __restrict__ idx, short* __restrict__ gxHi, short* __restrict__ gxLo) {
    int b = blockIdx.x;
    int tid = threadIdx.x, lane = tid & 63, wave = tid >> 6;
    __shared__ float s_t2[UDIM];
    __shared__ float s_v[UDIM];
    __shared__ float s_attn[SLEN];
    __shared__ float s_part[7][128][9];  // pad 9 floats: conflict-free combine
    for (int u = tid; u < UDIM; u += 1024) {
        s_t2[u] = tmp2[(size_t)b * UDIM + u];
        s_v[u] = V_W[u];
    }
    __syncthreads();
    for (int s = wave; s < SLEN; s += 16) {
        const float4* ep4 = (const float4*)(encProj + ((size_t)b * SLEN + s) * UDIM);
        float p = 0.f;
        for (int u4 = lane; u4 < UDIM / 4; u4 += 64) {
            float4 e = ep4[u4];
            int u = 4 * u4;
            p += tanhf_fast(e.x + s_t2[u]) * s_v[u] +
                 tanhf_fast(e.y + s_t2[u + 1]) * s_v[u + 1] +
                 tanhf_fast(e.z + s_t2[u + 2]) * s_v[u + 2] +
                 tanhf_fast(e.w + s_t2[u + 3]) * s_v[u + 3];
        }
#pragma unroll
        for (int off = 32; off > 0; off >>= 1) p += __shfl_xor(p, off);
        if (lane == 0) s_attn[s] = p + V_b[0];
    }
    __syncthreads();
    if (tid < 64) {
        float v = s_attn[tid];
        float mx = v;
#pragma unroll
        for (int off = 32; off > 0; off >>= 1) mx = fmaxf(mx, __shfl_xor(mx, off));
        float e = expf(v - mx);
        float sum = e;
#pragma unroll
        for (int off = 32; off > 0; off >>= 1) sum += __shfl_xor(sum, off);
        s_attn[tid] = e / sum;
    }
    __syncthreads();
    {
        int grp = tid >> 7, tu = tid & 127;  // 8 s-groups x 128 u-threads
        int u0 = tu * 8;
        float a[8] = {0, 0, 0, 0, 0, 0, 0, 0};
        const short8* hi8 = (const short8*)eaHi;
        const short8* lo8 = (const short8*)eaLo;
        int lanePart = 16 * ((u0 >> 3) & 3);
        int colPart = u0 >> 5;
        for (int s = grp * 8; s < grp * 8 + 8; s++) {
            int r = b * SLEN + s;
            size_t ch = ((size_t)(r >> 4) * (UDIM >> 5) + colPart) * 64 + (r & 15) + lanePart;
            S8 h, l;
            h.v = hi8[ch];
            l.v = lo8[ch];
            float w = s_attn[s];
#pragma unroll
            for (int j = 0; j < 8; j++) a[j] += w * (bf2f(h.s[j]) + bf2f(l.s[j]));
        }
        if (grp) {
#pragma unroll
            for (int j = 0; j < 8; j++) s_part[grp - 1][tu][j] = a[j];
        }
        __syncthreads();
        if (tid < 128) {
#pragma unroll
            for (int gg = 0; gg < 7; gg++)
#pragma unroll
                for (int j = 0; j < 8; j++) a[j] += s_part[gg][tu][j];
            writeSplit8(gxHi, gxLo, pkChunk(b, u0, GXW), a);
        } else if (tid < 192) {
            int e0 = (tid - 128) * 8;
            int ib = idx[b];
            const float* row = o2hT + (size_t)ib * EDIM + e0;
            float v[8];
#pragma unroll
            for (int j = 0; j < 8; j++) v[j] = row[j];
            writeSplit8(gxHi, gxLo, pkChunk(b, UDIM + e0, GXW), v);
        }
    }
}

// ---------------------------------------------------------------------------
// Merged: pred=h@fc^T+b + parallel first-max argmax (blocks 0..15) AND
// tmp2=h@W2^T+b for the next step (blocks 16..143).
// ---------------------------------------------------------------------------
__global__ __launch_bounds__(256) void fcw2(
    const short8* __restrict__ hHi, const short8* __restrict__ hLo,
    const short8* __restrict__ fcH, const short8* __restrict__ fcL,
    const float* __restrict__ fc_b, float* __restrict__ pred,
    int* __restrict__ idx,
    const short8* __restrict__ w2H, const short8* __restrict__ w2L,
    const float* __restrict__ W2_b, float* __restrict__ tmp2) {
    __shared__ float sP[16][129];
    int tid = threadIdx.x, lane = tid & 63, wave = tid >> 6;
    if (blockIdx.x < 16) {
        int fm = blockIdx.x;
        const short8* ah = hHi + (size_t)fm * 32 * 64 + lane;
        const short8* al = hLo + (size_t)fm * 32 * 64 + lane;
        int n0 = 2 * wave, n1 = 2 * wave + 1;
        const short8* w0h = fcH + (size_t)n0 * 32 * 64 + lane;
        const short8* w0l = fcL + (size_t)n0 * 32 * 64 + lane;
        const short8* w1h = fcH + (size_t)n1 * 32 * 64 + lane;
        const short8* w1l = fcL + (size_t)n1 * 32 * 64 + lane;
        f32x4 a0 = {0,0,0,0}, a1 = {0,0,0,0};
        for (int kt = 0; kt < 32; kt++) {
            size_t o = (size_t)kt * 64;
            short8 AH = ah[o], AL = al[o];
            short8 W0H = w0h[o], W0L = w0l[o], W1H = w1h[o], W1L = w1l[o];
            MFMA(a0, AH, W0H); MFMA(a1, AH, W1H);
            MFMA(a0, AH, W0L); MFMA(a1, AH, W1L);
            MFMA(a0, AL, W0H); MFMA(a1, AL, W1H);
        }
        int cn = lane & 15, rsub = (lane >> 4) << 2;
#pragma unroll
        for (int j = 0; j < 4; j++) {
            sP[rsub + j][n0 * 16 + cn] = a0[j] + fc_b[n0 * 16 + cn];
            sP[rsub + j][n1 * 16 + cn] = a1[j] + fc_b[n1 * 16 + cn];
        }
        __syncthreads();
        {
            int row = tid >> 4, c0 = (tid & 15) * 8;
            float* pr = pred + (size_t)(fm * 16 + row) * VOUTD;
#pragma unroll
            for (int j = 0; j < 8; j++) pr[c0 + j] = sP[row][c0 + j];
        }
        if (tid < 128) {
            // 8 lanes per row, first-max semantics (strict > in scan order,
            // smaller index wins ties across segments)
            int row = tid >> 3, seg = tid & 7;
            float v = -1e30f;
            int bi = 0;
            int c0 = seg * 16;
            for (int j = c0; j < c0 + 16; j++) {
                float w = sP[row][j];
                if (w > v) { v = w; bi = j; }
            }
#pragma unroll
            for (int off = 1; off < 8; off <<= 1) {
                float ov = __shfl_xor(v, off);
                int obi = __shfl_xor(bi, off);
                if (ov > v || (ov == v && obi < bi)) { v = ov; bi = obi; }
            }
            if (seg == 0) idx[fm * 16 + row] = bi;
        }
    } else {
        int lin = blockIdx.x - 16;       // 0..127
        int bx = lin & 7, by = lin >> 3; // bm32 grid (8, 16)
        int m16 = bx * 2 + (wave & 1);
        int n16 = by * 4 + (wave >> 1) * 2;
        const short8* ah = hHi + (size_t)m16 * 32 * 64 + lane;
        const short8* al = hLo + (size_t)m16 * 32 * 64 + lane;
        const short8* w0h = w2H + (size_t)n16 * 32 * 64 + lane;
        const short8* w1h = w0h + (size_t)32 * 64;
        const short8* w0l = w2L + (size_t)n16 * 32 * 64 + lane;
        const short8* w1l = w0l + (size_t)32 * 64;
        f32x4 a0 = {0,0,0,0}, a1 = {0,0,0,0};
        for (int kt = 0; kt < 32; kt++) {
            size_t o = (size_t)kt * 64;
            short8 AH = ah[o], AL = al[o];
            short8 W0H = w0h[o], W0L = w0l[o], W1H = w1h[o], W1L = w1l[o];
            MFMA(a0, AH, W0H); MFMA(a1, AH, W1H);
            MFMA(a0, AH, W0L); MFMA(a1, AH, W1L);
            MFMA(a0, AL, W0H); MFMA(a1, AL, W1H);
        }
        int rsub = (lane >> 4) * 4, cn = lane & 15;
        float b0 = W2_b[(n16 + 0) * 16 + cn];
        float b1 = W2_b[(n16 + 1) * 16 + cn];
#pragma unroll
        for (int r = 0; r < 4; r++) {
            int row = m16 * 16 + rsub + r;
            tmp2[(size_t)row * UDIM + (n16 + 0) * 16 + cn] = a0[r] + b0;
            tmp2[(size_t)row * UDIM + (n16 + 1) * 16 + cn] = a1[r] + b1;
        }
    }
}

// ---------------------------------------------------------------------------
extern "C" void kernel_launch(void* const* d_in, const int* in_sizes, int n_in,
                              void* d_out, int out_size, void* d_ws, size_t ws_size,
                              hipStream_t stream) {
    const float* x       = (const float*)d_in[0];
    const int*   x_len   = (const int*)d_in[1];
    const float* enc_Wih = (const float*)d_in[2];
    const float* enc_Whh = (const float*)d_in[3];
    const float* enc_bih = (const float*)d_in[4];
    const float* enc_bhh = (const float*)d_in[5];
    const float* dec_Wih = (const float*)d_in[6];
    const float* dec_Whh = (const float*)d_in[7];
    const float* dec_bih = (const float*)d_in[8];
    const float* dec_bhh = (const float*)d_in[9];
    const float* o2h_W   = (const float*)d_in[10];
    const float* o2h_b   = (const float*)d_in[11];
    const float* fc_W    = (const float*)d_in[12];
    const float* fc_b    = (const float*)d_in[13];
    const float* W1_W    = (const float*)d_in[14];
    const float* W1_b    = (const float*)d_in[15];
    const float* W2_W    = (const float*)d_in[16];
    const float* W2_b    = (const float*)d_in[17];
    const float* V_W     = (const float*)d_in[18];
    const float* V_b     = (const float*)d_in[19];
    float* out = (float*)d_out;

    char* p = (char*)d_ws;
    auto alloc = [&](size_t bytes) -> char* {
        char* q = p;
        p += (bytes + 255) & ~(size_t)255;
        return q;
    };
    float* hAF  = (float*)alloc((size_t)BATCH * UDIM * 4);
    float* hBF  = (float*)alloc((size_t)BATCH * UDIM * 4);
    short* hAH  = (short*)alloc((size_t)BATCH * UDIM * 2);
    short* hAL  = (short*)alloc((size_t)BATCH * UDIM * 2);
    short* hBH  = (short*)alloc((size_t)BATCH * UDIM * 2);
    short* hBL  = (short*)alloc((size_t)BATCH * UDIM * 2);
    float* tmp2 = (float*)alloc((size_t)BATCH * UDIM * 4);
    short* gxHi = (short*)alloc((size_t)BATCH * GXW * 2);
    short* gxLo = (short*)alloc((size_t)BATCH * GXW * 2);
    short* encAHi = (short*)alloc((size_t)BATCH * SLEN * UDIM * 2);
    short* encALo = (short*)alloc((size_t)BATCH * SLEN * UDIM * 2);
    float* encProjF = (float*)alloc((size_t)BATCH * SLEN * UDIM * 4);
    float* gihBuf = (float*)alloc((size_t)8 * BATCH * U3 * 4);
    short* eWihH = (short*)alloc((size_t)U3 * VIND * 2);
    short* eWihL = (short*)alloc((size_t)U3 * VIND * 2);
    short* eWrH = (short*)alloc((size_t)UDIM * UDIM * 2);
    short* eWrL = (short*)alloc((size_t)UDIM * UDIM * 2);
    short* eWzH = (short*)alloc((size_t)UDIM * UDIM * 2);
    short* eWzL = (short*)alloc((size_t)UDIM * UDIM * 2);
    short* eWnH = (short*)alloc((size_t)UDIM * UDIM * 2);
    short* eWnL = (short*)alloc((size_t)UDIM * UDIM * 2);
    short* dWrH = (short*)alloc((size_t)UDIM * 2560 * 2);
    short* dWrL = (short*)alloc((size_t)UDIM * 2560 * 2);
    short* dWzH = (short*)alloc((size_t)UDIM * 2560 * 2);
    short* dWzL = (short*)alloc((size_t)UDIM * 2560 * 2);
    short* dWnhH = (short*)alloc((size_t)UDIM * UDIM * 2);
    short* dWnhL = (short*)alloc((size_t)UDIM * UDIM * 2);
    short* dWniH = (short*)alloc((size_t)UDIM * GXW * 2);
    short* dWniL = (short*)alloc((size_t)UDIM * GXW * 2);
    short* w1Hi = (short*)alloc((size_t)UDIM * UDIM * 2);
    short* w1Lo = (short*)alloc((size_t)UDIM * UDIM * 2);
    short* w2Hi = (short*)alloc((size_t)UDIM * UDIM * 2);
    short* w2Lo = (short*)alloc((size_t)UDIM * UDIM * 2);
    short* fcHi = (short*)alloc((size_t)VOUTD * UDIM * 2);
    short* fcLo = (short*)alloc((size_t)VOUTD * UDIM * 2);
    short* xHi  = (short*)alloc((size_t)SLEN * BATCH * VIND * 2);
    short* xLo  = (short*)alloc((size_t)SLEN * BATCH * VIND * 2);
    int*   idx  = (int*)alloc(BATCH * 4);
    float* o2hT = (float*)alloc((size_t)VOUTD * EDIM * 4);

    init_kernel<<<(BATCH * UDIM + 255) / 256, 256, 0, stream>>>(
        hAF, hAH, hAL, out, idx, o2h_W, o2h_b, o2hT);

    // ---- single packing kernel for all weights + x ----
    {
        PackArgs pa;
        int cs = 0, n = 0;
        auto seg = [&](const float* sA, int KA, int offA, const float* sB, int KB,
                       int offB, short* Hi, short* Lo, int R) {
            pa.s[n] = {sA, sB, Hi, Lo, KA, KB, offA, offB, cs};
            cs += R * (KA + KB) / 8;
            n++;
        };
        seg(enc_Wih, VIND, 0, nullptr, 0, 0, eWihH, eWihL, U3);
        seg(enc_Whh, UDIM, 0, nullptr, 0, 0, eWrH, eWrL, UDIM);
        seg(enc_Whh, UDIM, UDIM, nullptr, 0, 0, eWzH, eWzL, UDIM);
        seg(enc_Whh, UDIM, 2 * UDIM, nullptr, 0, 0, eWnH, eWnL, UDIM);
        seg(dec_Whh, UDIM, 0, dec_Wih, GXW, 0, dWrH, dWrL, UDIM);
        seg(dec_Whh, UDIM, UDIM, dec_Wih, GXW, UDIM, dWzH, dWzL, UDIM);
        seg(dec_Whh, UDIM, 2 * UDIM, nullptr, 0, 0, dWnhH, dWnhL, UDIM);
        seg(dec_Wih, GXW, 2 * UDIM, nullptr, 0, 0, dWniH, dWniL, UDIM);
        seg(W1_W, UDIM, 0, nullptr, 0, 0, w1Hi, w1Lo, UDIM);
        seg(W2_W, UDIM, 0, nullptr, 0, 0, w2Hi, w2Lo, UDIM);
        seg(fc_W, UDIM, 0, nullptr, 0, 0, fcHi, fcLo, VOUTD);
        seg(x, VIND, 0, nullptr, 0, 0, xHi, xLo, SLEN * BATCH);
        pack_all<<<(cs + 255) / 256, 256, 0, stream>>>(pa, cs);
    }

    // ---- encoder: 8 chunks of (gi chunk-GEMM + 8 fused GRU steps) ----
    float* hcF = hAF; float* hnF = hBF;
    short *hcH = hAH, *hcL = hAL, *hnH = hBH, *hnL = hBL;
    for (int c = 0; c < 8; c++) {
        gemm_w<<<dim3(32, 24), 256, 0, stream>>>(
            (const short8*)xHi + (size_t)c * 128 * 4 * 64,
            (const short8*)xLo + (size_t)c * 128 * 4 * 64,
            (const short8*)eWihH, (const short8*)eWihL,
            nullptr, gihBuf, VIND / 32, U3);
        for (int tt = 0; tt < 8; tt++) {
            int t = c * 8 + tt;
            enc_gru3<<<dim3(64, 4), 768, 0, stream>>>(
                (const short8*)hcH, (const short8*)hcL,
                (const short8*)eWrH, (const short8*)eWrL,
                (const short8*)eWzH, (const short8*)eWzL,
                (const short8*)eWnH, (const short8*)eWnL,
                gihBuf, enc_bih, enc_bhh, hcF, hnF, hnH, hnL,
                encAHi, encALo, x_len, t);
            { float* tf = hcF; hcF = hnF; hnF = tf; }
            { short* th = hcH; hcH = hnH; hnH = th; th = hcL; hcL = hnL; hnL = th; }
        }
    }

    // ---- enc_proj = enc_out @ W1^T + W1_b (fp32, BN=128 blocks) ----
    gemm_w<<<dim3(SLEN * BATCH / 64, UDIM / 128), 256, 0, stream>>>(
        (const short8*)encAHi, (const short8*)encALo,
        (const short8*)w1Hi, (const short8*)w1Lo,
        W1_b, encProjF, UDIM / 32, UDIM);

    // ---- initial tmp2 from encoder hidden ----
    gemm_bm32<<<dim3(BATCH / 32, UDIM / 64), 256, 0, stream>>>(
        (const short8*)hcH, (const short8*)hcL,
        (const short8*)w2Hi, (const short8*)w2Lo,
        W2_b, tmp2, UDIM / 32, UDIM);

    // ---- greedy decode: 24 steps x 3 dispatches ----
    for (int st = 0; st < TDEC - 1; st++) {
        attn_ctx<<<BATCH, 1024, 0, stream>>>(
            encProjF, encAHi, encALo, tmp2, V_W, V_b, o2hT, idx, gxHi, gxLo);
        dec_gru3<<<dim3(64, 4), 768, 0, stream>>>(
            (const short8*)hcH, (const short8*)hcL,
            (const short8*)gxHi, (const short8*)gxLo,
            (const short8*)dWrH, (const short8*)dWrL,
            (const short8*)dWzH, (const short8*)dWzL,
            (const short8*)dWnhH, (const short8*)dWnhL,
            (const short8*)dWniH, (const short8*)dWniL,
            dec_bih, dec_bhh, hcF, hnF, hnH, hnL);
        float* pred = out + (size_t)(1 + st) * BATCH * VOUTD;
        fcw2<<<144, 256, 0, stream>>>(
            (const short8*)hnH, (const short8*)hnL,
            (const short8*)fcHi, (const short8*)fcLo,
            fc_b, pred, idx,
            (const short8*)w2Hi, (const short8*)w2Lo, W2_b, tmp2);
        { float* tf = hcF; hcF = hnF; hnF = tf; }
        { short* th = hcH; hcH = hnH; hnH = th; th = hcL; hcL = hnL; hnL = th; }
    }
}